// Round 2
// baseline (2593.077 us; speedup 1.0000x reference)
//
#include <hip/hip_runtime.h>
#include <hip/hip_bf16.h>
#include <cstdint>
#include <cstddef>

// ---------------------------------------------------------------------------
// Transformer: L=8, B=8, N=1024, W=768, H=12, C=64.  h kept fp32 in d_out.
// All GEMMs bf16-MFMA (16x16x32), fp32 accum. LN/softmax/GELU fp32.
// ---------------------------------------------------------------------------

typedef __attribute__((ext_vector_type(8))) short bf16x8;   // 8 bf16 = 4 VGPRs
typedef __attribute__((ext_vector_type(4))) float f32x4;

#define MFMA16(a, b, c) __builtin_amdgcn_mfma_f32_16x16x32_bf16((a), (b), (c), 0, 0, 0)

__device__ __forceinline__ void gld_lds16(const void* g, void* l) {
    // async global->LDS, 16B per lane; LDS dest must be uniform_base + lane*16
    __builtin_amdgcn_global_load_lds((const __attribute__((address_space(1))) unsigned int*)g,
                                     (__attribute__((address_space(3))) unsigned int*)l,
                                     16, 0, 0);
}

__device__ __forceinline__ unsigned short f32_to_bf16_bits(float f) {
    unsigned u = __builtin_bit_cast(unsigned, f);
    u += 0x7fffu + ((u >> 16) & 1u);      // RNE; inputs are finite
    return (unsigned short)(u >> 16);
}

__device__ __forceinline__ unsigned pack_bf2(float a, float b) {
    return (unsigned)f32_to_bf16_bits(a) | ((unsigned)f32_to_bf16_bits(b) << 16);
}

__device__ __forceinline__ unsigned cvt_pk_bf16(float lo, float hi) {
    // dst = { [15:0]=bf16(lo), [31:16]=bf16(hi) }, RNE — same as pack_bf2
    unsigned r;
    asm("v_cvt_pk_bf16_f32 %0, %1, %2" : "=v"(r) : "v"(lo), "v"(hi));
    return r;
}

// ---------------------------------------------------------------------------
// 256x256 8-phase GEMM (T2+T3+T4+T5 template, §5 gemm_256sq_8phase):
// C[M,N] = A[M,K](bf16) @ Bt[N,K]^T(bf16) + bias (+GELU), bf16 out.
// M == 8192 (32 m-tiles), N % 256 == 0, K % 64 == 0 (>= 128).
// 512 threads = 8 waves (2M x 4N), per-wave output 128x64, acc[8][4].
// LDS 128 KiB: A/B tiles [256][64] double-buffered, XOR-8 swizzle applied on
// the per-lane GLOBAL source (slot' = slot ^ (row&7)), linear gld_lds dest,
// same XOR on every ds_read_b128 -> conflict-free frag reads (T2 / G21).
// Per K-tile: 4 phases, each {ds_read subtile; stage; s_barrier; lgkmcnt(0);
// setprio(1); 16 MFMA (one C-quadrant); setprio(0); s_barrier}.  Staging of
// tile t+1 is front-loaded into phases 1-2 of tile t; single vmcnt(0) per
// K-tile at phase-4 end (2-3 phases after issue) — depth-1, provably race-free.
// ---------------------------------------------------------------------------
template <bool GELU>
__global__ __launch_bounds__(512, 2) void gemm256(const __hip_bfloat16* __restrict__ A,
                                                  const __hip_bfloat16* __restrict__ Bt,
                                                  const float* __restrict__ bias,
                                                  __hip_bfloat16* __restrict__ outh,
                                                  int N, int K) {
    __shared__ __hip_bfloat16 lA[2][256 * 64];   // 32 KB x2
    __shared__ __hip_bfloat16 lB[2][256 * 64];   // 32 KB x2
    const int t = threadIdx.x;
    const int w = t >> 6, l = t & 63;
    const int lr = l & 15, lg = l >> 4;
    const int wr = w >> 2, wc = w & 3;           // 2 x 4 wave grid
    // XCD-aware decode: 32 m-tiles, 4 per XCD; n fastest within an XCD
    const int bid = blockIdx.x;
    const int xcd = bid & 7, local = bid >> 3;
    const int m0 = (xcd * 4 + (local & 3)) * 256;
    const int n0 = (local >> 2) * 256;

    // stage: tile [256][64] = 2048 chunks of 16B; thread owns c = t + j*512.
    // chunk c: row=c>>3, phys slot=c&7; global col = (slot ^ (row&7))*8.
    const int srow = t >> 3, sslot = t & 7;
#define STAGE_A(buf, kt)                                                            \
    {                                                                               \
        _Pragma("unroll") for (int j = 0; j < 4; j++) {                             \
            const int row = srow + j * 64;                                          \
            gld_lds16(&A[(size_t)(m0 + row) * K + (kt) * 64 + ((sslot ^ (row & 7)) << 3)], \
                      &lA[buf][(t + j * 512) * 8]);                                 \
        }                                                                           \
    }
#define STAGE_B(buf, kt)                                                            \
    {                                                                               \
        _Pragma("unroll") for (int j = 0; j < 4; j++) {                             \
            const int row = srow + j * 64;                                          \
            gld_lds16(&Bt[(size_t)(n0 + row) * K + (kt) * 64 + ((sslot ^ (row & 7)) << 3)], \
                      &lB[buf][(t + j * 512) * 8]);                                 \
        }                                                                           \
    }

    f32x4 acc[8][4];
#pragma unroll
    for (int i = 0; i < 8; i++)
#pragma unroll
        for (int j = 0; j < 4; j++) acc[i][j] = (f32x4){0.f, 0.f, 0.f, 0.f};

    // prologue: stage K-tile 0 into buf0; full drain (once)
    STAGE_A(0, 0);
    STAGE_B(0, 0);
    __syncthreads();

    const int NT = K >> 6;
    for (int kt = 0; kt < NT; ++kt) {
        const int cur = kt & 1;
        const bool more = (kt + 1 < NT);
        const __hip_bfloat16* sA = lA[cur];
        const __hip_bfloat16* sB = lB[cur];
        bf16x8 af[4][2], bf[4][2];

        // ---- phase 1: ds-read A(mh0) 8 + B(nh0) 4; stage A(kt+1); MFMA q(0,0)
#pragma unroll
        for (int mt = 0; mt < 4; mt++)
#pragma unroll
            for (int ks = 0; ks < 2; ks++) {
                const int row = wr * 128 + mt * 16 + lr;
                af[mt][ks] = *(const bf16x8*)&sA[row * 64 + ((((ks << 2) | lg) ^ (row & 7)) << 3)];
            }
#pragma unroll
        for (int nt = 0; nt < 2; nt++)
#pragma unroll
            for (int ks = 0; ks < 2; ks++) {
                const int row = wc * 64 + nt * 16 + lr;
                bf[nt][ks] = *(const bf16x8*)&sB[row * 64 + ((((ks << 2) | lg) ^ (row & 7)) << 3)];
            }
        if (more) STAGE_A(cur ^ 1, kt + 1);
        __builtin_amdgcn_s_barrier();
        asm volatile("s_waitcnt lgkmcnt(0)" ::: "memory");
        __builtin_amdgcn_sched_barrier(0);
        __builtin_amdgcn_s_setprio(1);
#pragma unroll
        for (int mt = 0; mt < 4; mt++)
#pragma unroll
            for (int nt = 0; nt < 2; nt++)
#pragma unroll
                for (int ks = 0; ks < 2; ks++)
                    acc[mt][nt] = MFMA16(af[mt][ks], bf[nt][ks], acc[mt][nt]);
        __builtin_amdgcn_s_setprio(0);
        __builtin_amdgcn_s_barrier();

        // ---- phase 2: ds-read B(nh1) 4; stage B(kt+1); MFMA q(0,1)
#pragma unroll
        for (int nt = 2; nt < 4; nt++)
#pragma unroll
            for (int ks = 0; ks < 2; ks++) {
                const int row = wc * 64 + nt * 16 + lr;
                bf[nt][ks] = *(const bf16x8*)&sB[row * 64 + ((((ks << 2) | lg) ^ (row & 7)) << 3)];
            }
        if (more) STAGE_B(cur ^ 1, kt + 1);
        __builtin_amdgcn_s_barrier();
        asm volatile("s_waitcnt lgkmcnt(0)" ::: "memory");
        __builtin_amdgcn_sched_barrier(0);
        __builtin_amdgcn_s_setprio(1);
#pragma unroll
        for (int mt = 0; mt < 4; mt++)
#pragma unroll
            for (int nt = 2; nt < 4; nt++)
#pragma unroll
                for (int ks = 0; ks < 2; ks++)
                    acc[mt][nt] = MFMA16(af[mt][ks], bf[nt][ks], acc[mt][nt]);
        __builtin_amdgcn_s_setprio(0);
        __builtin_amdgcn_s_barrier();

        // ---- phase 3: ds-read A(mh1) 8 (overwrite af); MFMA q(1,1)
#pragma unroll
        for (int mt = 0; mt < 4; mt++)
#pragma unroll
            for (int ks = 0; ks < 2; ks++) {
                const int row = wr * 128 + 64 + mt * 16 + lr;
                af[mt][ks] = *(const bf16x8*)&sA[row * 64 + ((((ks << 2) | lg) ^ (row & 7)) << 3)];
            }
        __builtin_amdgcn_s_barrier();
        asm volatile("s_waitcnt lgkmcnt(0)" ::: "memory");
        __builtin_amdgcn_sched_barrier(0);
        __builtin_amdgcn_s_setprio(1);
#pragma unroll
        for (int mt = 0; mt < 4; mt++)
#pragma unroll
            for (int nt = 2; nt < 4; nt++)
#pragma unroll
                for (int ks = 0; ks < 2; ks++)
                    acc[4 + mt][nt] = MFMA16(af[mt][ks], bf[nt][ks], acc[4 + mt][nt]);
        __builtin_amdgcn_s_setprio(0);
        __builtin_amdgcn_s_barrier();

        // ---- phase 4: no reads; MFMA q(1,0); drain stage before buffer swap
        __builtin_amdgcn_s_setprio(1);
#pragma unroll
        for (int mt = 0; mt < 4; mt++)
#pragma unroll
            for (int nt = 0; nt < 2; nt++)
#pragma unroll
                for (int ks = 0; ks < 2; ks++)
                    acc[4 + mt][nt] = MFMA16(af[mt][ks], bf[nt][ks], acc[4 + mt][nt]);
        __builtin_amdgcn_s_setprio(0);
        asm volatile("s_waitcnt vmcnt(0)" ::: "memory");
        __builtin_amdgcn_sched_barrier(0);
        __builtin_amdgcn_s_barrier();
    }
#undef STAGE_A
#undef STAGE_B

    // epilogue: C/D layout col=lane&15, row=(lane>>4)*4+reg
#pragma unroll
    for (int nt = 0; nt < 4; nt++) {
        const int col = n0 + wc * 64 + nt * 16 + lr;
        const float bv = bias[col];
#pragma unroll
        for (int mt = 0; mt < 8; mt++) {
#pragma unroll
            for (int r = 0; r < 4; r++) {
                const int row = m0 + wr * 128 + mt * 16 + lg * 4 + r;
                float v = acc[mt][nt][r] + bv;
                if (GELU) v = 0.5f * v * (1.f + erff(v * 0.70710678118654752f));
                outh[(size_t)row * N + col] = __float2bfloat16(v);
            }
        }
    }
}

// ---------------------------------------------------------------------------
// 128x128 GEMM (m97 structure) — kept for the low-N shapes (O-proj, PR) where
// 256^2 tiling would idle most CUs (96 blocks on 256 CUs).
// C[M,N] = A[M,K](bf16) @ Bt[N,K]^T(bf16) + bias; residual(fp32, in-place ok),
// fp32 out.  M == 8192 (64 m-tiles), N % 128 == 0, K % 64 == 0.
// ---------------------------------------------------------------------------
template <bool RES, bool GELU, bool WF, bool WH>
__global__ __launch_bounds__(256) void gemm_bt(const __hip_bfloat16* __restrict__ A,
                                               const __hip_bfloat16* __restrict__ Bt,
                                               const float* __restrict__ bias,
                                               const float* __restrict__ res,
                                               float* __restrict__ outf,
                                               __hip_bfloat16* __restrict__ outh,
                                               int N, int K) {
    __shared__ __hip_bfloat16 lA0[128 * 32], lA1[128 * 32];
    __shared__ __hip_bfloat16 lB0[128 * 32], lB1[128 * 32];
    const int t = threadIdx.x;
    const int w = t >> 6, l = t & 63;
    const int lr = l & 15, lg = l >> 4;
    // XCD-aware decode: 64 m-tiles total, 8 per XCD
    const int bid = blockIdx.x;
    const int xcd = bid & 7;
    const int local = bid >> 3;
    const int m0 = (xcd * 8 + (local & 7)) * 128;
    const int n0 = (local >> 3) * 128;
    const int wm = (w & 1) * 64, wn = (w >> 1) * 64;

    f32x4 acc[4][4];
#pragma unroll
    for (int i = 0; i < 4; i++)
#pragma unroll
        for (int j = 0; j < 4; j++) acc[i][j] = (f32x4){0.f, 0.f, 0.f, 0.f};

    for (int k0 = 0; k0 < K; k0 += 64) {
        __syncthreads();
#pragma unroll
        for (int i = 0; i < 2; i++) {
            int c = t + i * 256;            // 512 chunks of 16B per 8KB tile
            int row = c >> 2, seg = c & 3;  // row-major [128][32] bf16
            const size_t ab = (size_t)(m0 + row) * K + k0 + seg * 8;
            const size_t bb = (size_t)(n0 + row) * K + k0 + seg * 8;
            gld_lds16(&A[ab],       &lA0[c * 8]);
            gld_lds16(&A[ab + 32],  &lA1[c * 8]);
            gld_lds16(&Bt[bb],      &lB0[c * 8]);
            gld_lds16(&Bt[bb + 32], &lB1[c * 8]);
        }
        __syncthreads();
#pragma unroll
        for (int hh = 0; hh < 2; hh++) {
            const __hip_bfloat16* sA = hh ? lA1 : lA0;
            const __hip_bfloat16* sB = hh ? lB1 : lB0;
            bf16x8 af[4], bfr[4];
#pragma unroll
            for (int mt = 0; mt < 4; mt++)
                af[mt] = *(const bf16x8*)&sA[(wm + mt * 16 + lr) * 32 + lg * 8];
#pragma unroll
            for (int nt = 0; nt < 4; nt++)
                bfr[nt] = *(const bf16x8*)&sB[(wn + nt * 16 + lr) * 32 + lg * 8];
#pragma unroll
            for (int mt = 0; mt < 4; mt++)
#pragma unroll
                for (int nt = 0; nt < 4; nt++)
                    acc[mt][nt] = MFMA16(af[mt], bfr[nt], acc[mt][nt]);
        }
    }

    // epilogue: C/D layout col=lane&15, row=(lane>>4)*4+reg  [m89/m91 verified]
#pragma unroll
    for (int nt = 0; nt < 4; nt++) {
        const int col = n0 + wn + nt * 16 + lr;
        const float bv = bias[col];
#pragma unroll
        for (int mt = 0; mt < 4; mt++) {
#pragma unroll
            for (int r = 0; r < 4; r++) {
                const int row = m0 + wm + mt * 16 + lg * 4 + r;
                const size_t idx = (size_t)row * N + col;
                float v = acc[mt][nt][r] + bv;
                if (RES) v += res[idx];
                if (GELU) v = 0.5f * v * (1.f + erff(v * 0.70710678118654752f));
                if (WF) outf[idx] = v;
                if (WH) outh[idx] = __float2bfloat16(v);
            }
        }
    }
}

// ---------------------------------------------------------------------------
// LayerNorm over W=768: one WAVE per row (4 rows/block), float4 loads, no LDS.
// fp32 in, bf16 out (affine).  grid = 2048.
// ---------------------------------------------------------------------------
__global__ __launch_bounds__(256) void ln_kernel(const float* __restrict__ h,
                                                 const float* __restrict__ g,
                                                 const float* __restrict__ b,
                                                 __hip_bfloat16* __restrict__ y) {
    const int t = threadIdx.x;
    const int w = t >> 6, l = t & 63;
    const int row = blockIdx.x * 4 + w;
    const float4* hr = (const float4*)(h + (size_t)row * 768);
    const float4* g4 = (const float4*)g;
    const float4* b4 = (const float4*)b;
    float4 x[3];
    float s = 0.f, q = 0.f;
#pragma unroll
    for (int j = 0; j < 3; j++) {
        x[j] = hr[l + j * 64];
        s += x[j].x + x[j].y + x[j].z + x[j].w;
        q += x[j].x * x[j].x + x[j].y * x[j].y + x[j].z * x[j].z + x[j].w * x[j].w;
    }
#pragma unroll
    for (int d = 1; d < 64; d <<= 1) {
        s += __shfl_xor(s, d);
        q += __shfl_xor(q, d);
    }
    const float mean = s * (1.f / 768.f);
    const float var = q * (1.f / 768.f) - mean * mean;
    const float rs = rsqrtf(var + 1e-5f);
    uint2* yr = (uint2*)(y + (size_t)row * 768);
#pragma unroll
    for (int j = 0; j < 3; j++) {
        const float4 gg = g4[l + j * 64], bb = b4[l + j * 64];
        float o0 = (x[j].x - mean) * rs * gg.x + bb.x;
        float o1 = (x[j].y - mean) * rs * gg.y + bb.y;
        float o2 = (x[j].z - mean) * rs * gg.z + bb.z;
        float o3 = (x[j].w - mean) * rs * gg.w + bb.w;
        yr[l + j * 64] = make_uint2(pack_bf2(o0, o1), pack_bf2(o2, o3));
    }
}

// ---------------------------------------------------------------------------
// Per-layer weight transpose+convert: W[K,N] fp32 -> Wt[N,K] bf16 (4 matrices).
// ---------------------------------------------------------------------------
__global__ __launch_bounds__(256) void transpose_weights(const float* __restrict__ sq,
                                                         const float* __restrict__ so,
                                                         const float* __restrict__ sf,
                                                         const float* __restrict__ sp,
                                                         __hip_bfloat16* __restrict__ dq,
                                                         __hip_bfloat16* __restrict__ dO,
                                                         __hip_bfloat16* __restrict__ df,
                                                         __hip_bfloat16* __restrict__ dp) {
    const int bid = blockIdx.x;
    const float* src;
    __hip_bfloat16* dst;
    int K, N, tloc;
    if (bid < 1728)      { src = sq; dst = dq; K = 768;  N = 2304; tloc = bid; }
    else if (bid < 2304) { src = so; dst = dO; K = 768;  N = 768;  tloc = bid - 1728; }
    else if (bid < 4608) { src = sf; dst = df; K = 768;  N = 3072; tloc = bid - 2304; }
    else                 { src = sp; dst = dp; K = 3072; N = 768;  tloc = bid - 4608; }
    const int ktiles = K / 32;
    const int k0 = (tloc % ktiles) * 32;
    const int n0 = (tloc / ktiles) * 32;
    const int t = threadIdx.x;
    __shared__ float tile[32][33];
#pragma unroll
    for (int p = 0; p < 4; p++) {
        int rr = p * 8 + (t >> 5);
        tile[rr][t & 31] = src[(size_t)(k0 + rr) * N + n0 + (t & 31)];
    }
    __syncthreads();
#pragma unroll
    for (int p = 0; p < 4; p++) {
        int rr = p * 8 + (t >> 5);
        dst[(size_t)(n0 + rr) * K + k0 + (t & 31)] = __float2bfloat16(tile[t & 31][rr]);
    }
}

// ---------------------------------------------------------------------------
// V transpose: qkv[b,n, h*192+128+c] -> vt[(b*12+h)*64+c, n]   (bf16 bits)
// ---------------------------------------------------------------------------
__global__ __launch_bounds__(256) void vt_transpose(const short* __restrict__ qkv,
                                                    short* __restrict__ vt) {
    const int bid = blockIdx.x;           // 96 bh * 64 tiles
    const int bh = bid >> 6, tau = bid & 63;
    const int b = bh / 12, h = bh % 12;
    const int ct = tau >> 5, nt = tau & 31;
    const int n0 = nt * 32, c0 = ct * 32;
    const int t = threadIdx.x;
    __shared__ short tile[32][33];
    const short* base = qkv + (size_t)(b * 1024 + n0) * 2304 + h * 192 + 128 + c0;
#pragma unroll
    for (int p = 0; p < 4; p++) {
        int rr = p * 8 + (t >> 5);
        tile[rr][t & 31] = base[(size_t)rr * 2304 + (t & 31)];
    }
    __syncthreads();
    short* ob = vt + (size_t)((b * 12 + h) * 64 + c0) * 1024 + n0;
#pragma unroll
    for (int p = 0; p < 4; p++) {
        int rr = p * 8 + (t >> 5);
        ob[(size_t)rr * 1024 + (t & 31)] = tile[t & 31][rr];
    }
}

// ---------------------------------------------------------------------------
// Flash attention, S^T formulation (round-0 version: swizzled gld_lds staging,
// cvt_pk packing, defer-max).  Workgroup = (64 queries, head, batch).
// ---------------------------------------------------------------------------
__global__ __launch_bounds__(256) void attn_kernel(const short* __restrict__ qkv,
                                                   const short* __restrict__ vt,
                                                   short* __restrict__ attnout) {
    // swizzle: 16 q-tiles of one (b,h) stay on one XCD (bid%8 round-robin)
    const int bid = blockIdx.x;           // 1536
    const int xcd = bid & 7, j = bid >> 3;
    const int bh = xcd * 12 + (j >> 4);
    const int qt = j & 15;
    const int b = bh / 12, hh = bh % 12;
    const int t = threadIdx.x, w = t >> 6, l = t & 63;
    const int lr = l & 15, lg = l >> 4;
    const int x7 = lr & 7;
    __shared__ short lK[64 * 64];          // [key][dim], linear, XOR-swizzled content
    __shared__ short lV[64 * 64];          // [dim][key], linear, XOR-swizzled content
    __shared__ short lP[4][16 * 64];       // per-wave P, [q][key], XOR-swizzled
    const int qw = qt * 64 + w * 16;

    // Q fragment (used as B operand), loaded once from global
    bf16x8 bq[2];
#pragma unroll
    for (int ks = 0; ks < 2; ks++)
        bq[ks] = *(const bf16x8*)&qkv[(size_t)(b * 1024 + qw + lr) * 2304 + hh * 192 + ks * 32 + lg * 8];

    // swizzled per-lane column offsets (shorts): logical 16B-slot s -> s^x7
    int col[2];
    col[0] = (lg ^ x7) * 8;
    col[1] = ((4 | lg) ^ x7) * 8;

    // staging: thread owns chunks c0=t, c1=t+256 of each 512x16B tile.
    const int c0 = t, c1 = t + 256;
    const int r0 = c0 >> 3, r1 = c1 >> 3;
    const int s0 = (c0 & 7) ^ (r0 & 7), s1 = (c1 & 7) ^ (r1 & 7);
    const short* gK0 = qkv + (size_t)(b * 1024 + r0) * 2304 + hh * 192 + 64 + s0 * 8;
    const short* gK1 = qkv + (size_t)(b * 1024 + r1) * 2304 + hh * 192 + 64 + s1 * 8;
    const short* gV0 = vt + (size_t)((b * 12 + hh) * 64 + r0) * 1024 + s0 * 8;
    const short* gV1 = vt + (size_t)((b * 12 + hh) * 64 + r1) * 1024 + s1 * 8;

    f32x4 o[4];
#pragma unroll
    for (int dt = 0; dt < 4; dt++) o[dt] = (f32x4){0.f, 0.f, 0.f, 0.f};
    const float cexp = 0.125f * 1.44269504088896f;  // scale^2 * log2(e)
    float cm = -1.0e30f;   // running c*max, per-lane query q=lr
    float lsum = 0.f;

    for (int kt = 0; kt < 16; kt++) {
        const int key0 = kt * 64;
        __syncthreads();
        gld_lds16(gK0 + (size_t)key0 * 2304, &lK[c0 * 8]);
        gld_lds16(gK1 + (size_t)key0 * 2304, &lK[c1 * 8]);
        gld_lds16(gV0 + key0, &lV[c0 * 8]);
        gld_lds16(gV1 + key0, &lV[c1 * 8]);
        __syncthreads();   // compiler drains vmcnt before s_barrier

        // S^T = K Q^T: lane holds S^T[key=nt*16+lg*4+r][q=lr]
        f32x4 s[4];
#pragma unroll
        for (int nt = 0; nt < 4; nt++) s[nt] = (f32x4){0.f, 0.f, 0.f, 0.f};
#pragma unroll
        for (int nt = 0; nt < 4; nt++)
#pragma unroll
            for (int ks = 0; ks < 2; ks++) {
                bf16x8 ak = *(const bf16x8*)&lK[(nt * 16 + lr) * 64 + col[ks]];
                s[nt] = MFMA16(ak, bq[ks], s[nt]);
            }

        // online softmax for query q=lr: in-lane over 16, then across lg groups
        float mx = s[0][0];
#pragma unroll
        for (int nt = 0; nt < 4; nt++)
#pragma unroll
            for (int r = 0; r < 4; r++) mx = fmaxf(mx, s[nt][r]);
        mx = fmaxf(mx, __shfl_xor(mx, 16));
        mx = fmaxf(mx, __shfl_xor(mx, 32));
        const float tm = mx * cexp;
        // defer-max: only rescale when the max grew by >8 in log2 domain.
        if (!__all(tm <= cm + 8.f)) {
            const float cmn = fmaxf(cm, tm);
            const float alpha = exp2f(cm - cmn);   // first tile: exp2(-inf)=0
            cm = cmn;
            lsum *= alpha;
            float af[4];
#pragma unroll
            for (int r = 0; r < 4; r++) af[r] = __shfl(alpha, lg * 4 + r);
#pragma unroll
            for (int dt = 0; dt < 4; dt++)
#pragma unroll
                for (int r = 0; r < 4; r++) o[dt][r] *= af[r];
        }
        float ps = 0.f;
#pragma unroll
        for (int nt = 0; nt < 4; nt++)
#pragma unroll
            for (int r = 0; r < 4; r++) {
                float p = exp2f(s[nt][r] * cexp - cm);   // bounded by 2^8
                s[nt][r] = p;
                ps += p;
            }
        ps += __shfl_xor(ps, 16);
        ps += __shfl_xor(ps, 32);
        lsum += ps;

        // pack P^T C-regs -> lP[w] as [q=lr][key], swizzled b64 halves
#pragma unroll
        for (int nt = 0; nt < 4; nt++) {
            unsigned pk0 = cvt_pk_bf16(s[nt][0], s[nt][1]);
            unsigned pk1 = cvt_pk_bf16(s[nt][2], s[nt][3]);
            const int S = nt * 2 + (lg >> 1);
            *(uint2*)&lP[w][lr * 64 + ((S ^ x7) << 3) + ((lg & 1) << 2)] = make_uint2(pk0, pk1);
        }

        // O += P V  (A-frag from lP b128; B-frag = V^T rows from lV b128)
#pragma unroll
        for (int kc = 0; kc < 2; kc++) {
            bf16x8 ap = *(const bf16x8*)&lP[w][lr * 64 + col[kc]];
#pragma unroll
            for (int dt = 0; dt < 4; dt++) {
                bf16x8 bv = *(const bf16x8*)&lV[(dt * 16 + lr) * 64 + col[kc]];
                o[dt] = MFMA16(ap, bv, o[dt]);
            }
        }
    }

    // epilogue: O[q=lg*4+r][c=dt*16+lr]; lsum for q'=lg*4+r from lane lg*4+r
    float inv[4];
#pragma unroll
    for (int r = 0; r < 4; r++) inv[r] = 1.f / __shfl(lsum, lg * 4 + r);
#pragma unroll
    for (int dt = 0; dt < 4; dt++)
#pragma unroll
        for (int r = 0; r < 4; r++)
            attnout[(size_t)(b * 1024 + qw + lg * 4 + r) * 768 + hh * 64 + dt * 16 + lr] =
                (short)f32_to_bf16_bits(o[dt][r] * inv[r]);
}

// ---------------------------------------------------------------------------
// Host
// ---------------------------------------------------------------------------
extern "C" void kernel_launch(void* const* d_in, const int* in_sizes, int n_in,
                              void* d_out, int out_size, void* d_ws, size_t ws_size,
                              hipStream_t stream) {
    const float* x    = (const float*)d_in[0];
    const float* Wqkv = (const float*)d_in[1];
    const float* bqkv = (const float*)d_in[2];
    const float* Wo   = (const float*)d_in[3];
    const float* bo   = (const float*)d_in[4];
    const float* Wfc  = (const float*)d_in[5];
    const float* bfc  = (const float*)d_in[6];
    const float* Wpr  = (const float*)d_in[7];
    const float* bpr  = (const float*)d_in[8];
    const float* g1   = (const float*)d_in[9];
    const float* b1   = (const float*)d_in[10];
    const float* g2   = (const float*)d_in[11];
    const float* b2   = (const float*)d_in[12];
    float* h = (float*)d_out;   // h lives in d_out throughout

    char* ws = (char*)d_ws;
    size_t off = 0;
    auto alloc = [&](size_t bytes) -> void* {
        void* p = ws + off;
        off += (bytes + 255) & ~(size_t)255;
        return p;
    };
    __hip_bfloat16* tQKV = (__hip_bfloat16*)alloc((size_t)2304 * 768 * 2);
    __hip_bfloat16* tO   = (__hip_bfloat16*)alloc((size_t)768 * 768 * 2);
    __hip_bfloat16* tFC  = (__hip_bfloat16*)alloc((size_t)3072 * 768 * 2);
    __hip_bfloat16* tPR  = (__hip_bfloat16*)alloc((size_t)768 * 3072 * 2);
    __hip_bfloat16* y    = (__hip_bfloat16*)alloc((size_t)8192 * 768 * 2);
    __hip_bfloat16* att  = (__hip_bfloat16*)alloc((size_t)8192 * 768 * 2);
    __hip_bfloat16* vtb  = (__hip_bfloat16*)alloc((size_t)8192 * 768 * 2);
    __hip_bfloat16* big  = (__hip_bfloat16*)alloc((size_t)8192 * 3072 * 2); // qkv & fc share
    __hip_bfloat16* qkvb = big;
    __hip_bfloat16* fcb  = big;

    hipMemcpyAsync(h, x, (size_t)8 * 1024 * 768 * 4, hipMemcpyDeviceToDevice, stream);

    for (int L = 0; L < 8; L++) {
        const float* wq = Wqkv + (size_t)L * 768 * 2304;
        const float* wo = Wo   + (size_t)L * 768 * 768;
        const float* wf = Wfc  + (size_t)L * 768 * 3072;
        const float* wp = Wpr  + (size_t)L * 3072 * 768;

        transpose_weights<<<6912, 256, 0, stream>>>(wq, wo, wf, wp, tQKV, tO, tFC, tPR);

        ln_kernel<<<2048, 256, 0, stream>>>(h, g1 + L * 768, b1 + L * 768, y);

        // QKV: M=8192, N=2304, K=768 -> 32 x 9 = 288 blocks (8-phase 256^2)
        gemm256<false><<<288, 512, 0, stream>>>(y, tQKV, bqkv + L * 2304, qkvb, 2304, 768);

        vt_transpose<<<6144, 256, 0, stream>>>((const short*)qkvb, (short*)vtb);

        attn_kernel<<<1536, 256, 0, stream>>>(
            (const short*)qkvb, (const short*)vtb, (short*)att);

        gemm_bt<true, false, true, false><<<6 * 64, 256, 0, stream>>>(
            att, tO, bo + L * 768, h, h, nullptr, 768, 768);

        ln_kernel<<<2048, 256, 0, stream>>>(h, g2 + L * 768, b2 + L * 768, y);

        // FC: M=8192, N=3072, K=768 -> 32 x 12 = 384 blocks (8-phase 256^2)
        gemm256<true><<<384, 512, 0, stream>>>(y, tFC, bfc + L * 3072, fcb, 3072, 768);

        gemm_bt<true, false, true, false><<<6 * 64, 256, 0, stream>>>(
            fcb, tPR, bpr + L * 768, h, h, nullptr, 768, 3072);
    }
}

// Round 3
// 2585.003 us; speedup vs baseline: 1.0031x; 1.0031x over previous
//
#include <hip/hip_runtime.h>
#include <hip/hip_bf16.h>
#include <cstdint>
#include <cstddef>

// ---------------------------------------------------------------------------
// Transformer: L=8, B=8, N=1024, W=768, H=12, C=64.  h kept fp32 in d_out.
// All GEMMs bf16-MFMA (16x16x32), fp32 accum. LN/softmax/GELU fp32.
// ---------------------------------------------------------------------------

typedef __attribute__((ext_vector_type(8))) short bf16x8;   // 8 bf16 = 4 VGPRs
typedef __attribute__((ext_vector_type(4))) float f32x4;

#define MFMA16(a, b, c) __builtin_amdgcn_mfma_f32_16x16x32_bf16((a), (b), (c), 0, 0, 0)

__device__ __forceinline__ void gld_lds16(const void* g, void* l) {
    // async global->LDS, 16B per lane; LDS dest must be uniform_base + lane*16
    __builtin_amdgcn_global_load_lds((const __attribute__((address_space(1))) unsigned int*)g,
                                     (__attribute__((address_space(3))) unsigned int*)l,
                                     16, 0, 0);
}

__device__ __forceinline__ unsigned short f32_to_bf16_bits(float f) {
    unsigned u = __builtin_bit_cast(unsigned, f);
    u += 0x7fffu + ((u >> 16) & 1u);      // RNE; inputs are finite
    return (unsigned short)(u >> 16);
}

__device__ __forceinline__ unsigned pack_bf2(float a, float b) {
    return (unsigned)f32_to_bf16_bits(a) | ((unsigned)f32_to_bf16_bits(b) << 16);
}

__device__ __forceinline__ unsigned cvt_pk_bf16(float lo, float hi) {
    // dst = { [15:0]=bf16(lo), [31:16]=bf16(hi) }, RNE — same as pack_bf2
    unsigned r;
    asm("v_cvt_pk_bf16_f32 %0, %1, %2" : "=v"(r) : "v"(lo), "v"(hi));
    return r;
}

// ---------------------------------------------------------------------------
// 256x256 8-phase GEMM with COUNTED vmcnt (T2+T3+T4+T5, m201/m218 ledger).
// C[M,N] = A[M,K](bf16) @ Bt[N,K]^T(bf16) + bias (+GELU), bf16 out.
// M == 8192 (32 m-tiles), N % 256 == 0, K % 64 == 0 (>= 128).
// 512 threads = 8 waves (2M x 4N).  LDS 128 KiB: [2 dbuf][2 half][128][64]
// for A and B, XOR-8 swizzle on the per-lane GLOBAL source, linear gld_lds
// dest, same XOR on ds_read_b128 -> 0 bank conflicts (verified round 2).
//
// Half/quadrant geometry: A-half0 = tile rows 0..127, A-half1 = 128..255;
// wave wr computes rows {wr*64..+63} (ph1/2) and {128+wr*64..+63} (ph3/4).
// B-half0 = rows 0..127: wave wc cols {wc*32..+31} (ph1/4); B-half1 =
// rows 128..255: cols {128+wc*32..+31} (ph2/3).
// Phase p consumes exactly one new half: ph1:{A0,B0} ph2:{B1} ph3:{A1} ph4:{}.
// Stage order for tile t+1 (one half per phase): A0@ph1 B0@ph2 B1@ph3 A1@ph4.
// vmcnt ledger (2 loads/half/thread, FIFO):
//   end ph1: out={B1,A1,A0'} =6, need B1  -> vmcnt(4)
//   end ph2: out={A1,A0',B0'}=6, need A1  -> vmcnt(4)
//   end ph3: no consumer next phase       -> no wait (barrier dropped too)
//   end ph4: out={A0',B0',B1',A1'}=8, need A0',B0' -> vmcnt(4)
// Never 0 in the main loop; >=2 half-tiles always in flight (T4).
// Last tile (no stages): vmcnt(2) @ph1, vmcnt(0) @ph2.
// ---------------------------------------------------------------------------
template <bool GELU>
__global__ __launch_bounds__(512, 2) void gemm256(const __hip_bfloat16* __restrict__ A,
                                                  const __hip_bfloat16* __restrict__ Bt,
                                                  const float* __restrict__ bias,
                                                  __hip_bfloat16* __restrict__ outh,
                                                  int N, int K) {
    __shared__ __hip_bfloat16 lA[2][2 * 128 * 64];   // [dbuf][half*8192 + row*64 + col]
    __shared__ __hip_bfloat16 lB[2][2 * 128 * 64];
    const int t = threadIdx.x;
    const int w = t >> 6, l = t & 63;
    const int lr = l & 15, lg = l >> 4;
    const int wr = w >> 2, wc = w & 3;           // 2 x 4 wave grid
    const int x7 = lr & 7;
    const int cs0 = ((lg) ^ x7) << 3;            // swizzled col offset, ks=0
    const int cs1 = ((4 | lg) ^ x7) << 3;        // swizzled col offset, ks=1
    // XCD-aware decode: 32 m-tiles, 4 per XCD; n fastest within an XCD
    const int bid = blockIdx.x;
    const int xcd = bid & 7, local = bid >> 3;
    const int m0 = (xcd * 4 + (local & 3)) * 256;
    const int n0 = (local >> 2) * 256;

    // stage one 128-row half: 1024 chunks of 16B; thread owns c = t + j*512.
    // chunk c: row_in_half = c>>3, phys slot = c&7; global col = (slot^(row&7))*8
    const int srow = t >> 3, sslot = t & 7;
#define STAGE_A(buf, kt, hf)                                                          \
    {                                                                                 \
        _Pragma("unroll") for (int j = 0; j < 2; j++) {                               \
            const int row = (hf) * 128 + srow + j * 64;                               \
            gld_lds16(&A[(size_t)(m0 + row) * K + (kt) * 64 + ((sslot ^ (row & 7)) << 3)], \
                      &lA[buf][(hf) * 8192 + (t + j * 512) * 8]);                     \
        }                                                                             \
    }
#define STAGE_B(buf, kt, hf)                                                          \
    {                                                                                 \
        _Pragma("unroll") for (int j = 0; j < 2; j++) {                               \
            const int row = (hf) * 128 + srow + j * 64;                               \
            gld_lds16(&Bt[(size_t)(n0 + row) * K + (kt) * 64 + ((sslot ^ (row & 7)) << 3)], \
                      &lB[buf][(hf) * 8192 + (t + j * 512) * 8]);                     \
        }                                                                             \
    }

    f32x4 acc[8][4];
#pragma unroll
    for (int i = 0; i < 8; i++)
#pragma unroll
        for (int j = 0; j < 4; j++) acc[i][j] = (f32x4){0.f, 0.f, 0.f, 0.f};

    // prologue: stage tile 0 (A0,B0,B1,A1); wait first two halves; barrier
    STAGE_A(0, 0, 0);
    STAGE_B(0, 0, 0);
    STAGE_B(0, 0, 1);
    STAGE_A(0, 0, 1);
    asm volatile("s_waitcnt vmcnt(4)" ::: "memory");
    __builtin_amdgcn_sched_barrier(0);
    __builtin_amdgcn_s_barrier();

    const int NT = K >> 6;
    for (int kt = 0; kt < NT; ++kt) {
        const int cur = kt & 1;
        const bool more = (kt + 1 < NT);
        const __hip_bfloat16* sA = lA[cur];
        const __hip_bfloat16* sB = lB[cur];
        bf16x8 af[4][2], bf[4][2];

        // ---- phase 1: read A0 (8) + B0 (4); stage A0(t+1); MFMA m-lo x n-lo
#pragma unroll
        for (int mt = 0; mt < 4; mt++) {
            const int ro = (wr * 64 + mt * 16 + lr) * 64;
            af[mt][0] = *(const bf16x8*)&sA[ro + cs0];
            af[mt][1] = *(const bf16x8*)&sA[ro + cs1];
        }
#pragma unroll
        for (int nt = 0; nt < 2; nt++) {
            const int ro = (wc * 32 + nt * 16 + lr) * 64;
            bf[nt][0] = *(const bf16x8*)&sB[ro + cs0];
            bf[nt][1] = *(const bf16x8*)&sB[ro + cs1];
        }
        if (more) STAGE_A(cur ^ 1, kt + 1, 0);
        __builtin_amdgcn_s_barrier();
        asm volatile("s_waitcnt lgkmcnt(0)" ::: "memory");
        __builtin_amdgcn_sched_barrier(0);
        __builtin_amdgcn_s_setprio(1);
#pragma unroll
        for (int mt = 0; mt < 4; mt++)
#pragma unroll
            for (int nt = 0; nt < 2; nt++)
#pragma unroll
                for (int ks = 0; ks < 2; ks++)
                    acc[mt][nt] = MFMA16(af[mt][ks], bf[nt][ks], acc[mt][nt]);
        __builtin_amdgcn_s_setprio(0);
        if (more) { asm volatile("s_waitcnt vmcnt(4)" ::: "memory"); }
        else      { asm volatile("s_waitcnt vmcnt(2)" ::: "memory"); }
        __builtin_amdgcn_sched_barrier(0);
        __builtin_amdgcn_s_barrier();

        // ---- phase 2: read B1 (4); stage B0(t+1); MFMA m-lo x n-hi
#pragma unroll
        for (int nt = 2; nt < 4; nt++) {
            const int ro = 8192 + (wc * 32 + (nt - 2) * 16 + lr) * 64;
            bf[nt][0] = *(const bf16x8*)&sB[ro + cs0];
            bf[nt][1] = *(const bf16x8*)&sB[ro + cs1];
        }
        if (more) STAGE_B(cur ^ 1, kt + 1, 0);
        __builtin_amdgcn_s_barrier();
        asm volatile("s_waitcnt lgkmcnt(0)" ::: "memory");
        __builtin_amdgcn_sched_barrier(0);
        __builtin_amdgcn_s_setprio(1);
#pragma unroll
        for (int mt = 0; mt < 4; mt++)
#pragma unroll
            for (int nt = 2; nt < 4; nt++)
#pragma unroll
                for (int ks = 0; ks < 2; ks++)
                    acc[mt][nt] = MFMA16(af[mt][ks], bf[nt][ks], acc[mt][nt]);
        __builtin_amdgcn_s_setprio(0);
        if (more) { asm volatile("s_waitcnt vmcnt(4)" ::: "memory"); }
        else      { asm volatile("s_waitcnt vmcnt(0)" ::: "memory"); }
        __builtin_amdgcn_sched_barrier(0);
        __builtin_amdgcn_s_barrier();

        // ---- phase 3: read A1 (8, overwrite af); stage B1(t+1); MFMA m-hi x n-hi
#pragma unroll
        for (int mt = 0; mt < 4; mt++) {
            const int ro = 8192 + (wr * 64 + mt * 16 + lr) * 64;
            af[mt][0] = *(const bf16x8*)&sA[ro + cs0];
            af[mt][1] = *(const bf16x8*)&sA[ro + cs1];
        }
        if (more) STAGE_B(cur ^ 1, kt + 1, 1);
        __builtin_amdgcn_s_barrier();
        asm volatile("s_waitcnt lgkmcnt(0)" ::: "memory");
        __builtin_amdgcn_sched_barrier(0);
        __builtin_amdgcn_s_setprio(1);
#pragma unroll
        for (int mt = 0; mt < 4; mt++)
#pragma unroll
            for (int nt = 2; nt < 4; nt++)
#pragma unroll
                for (int ks = 0; ks < 2; ks++)
                    acc[4 + mt][nt] = MFMA16(af[mt][ks], bf[nt][ks], acc[4 + mt][nt]);
        __builtin_amdgcn_s_setprio(0);
        // no vmcnt, no barrier: phase 4 is register-only

        // ---- phase 4: stage A1(t+1); MFMA m-hi x n-lo; counted drain; swap
        if (more) STAGE_A(cur ^ 1, kt + 1, 1);
        __builtin_amdgcn_s_setprio(1);
#pragma unroll
        for (int mt = 0; mt < 4; mt++)
#pragma unroll
            for (int nt = 0; nt < 2; nt++)
#pragma unroll
                for (int ks = 0; ks < 2; ks++)
                    acc[4 + mt][nt] = MFMA16(af[mt][ks], bf[nt][ks], acc[4 + mt][nt]);
        __builtin_amdgcn_s_setprio(0);
        if (more) { asm volatile("s_waitcnt vmcnt(4)" ::: "memory"); }
        __builtin_amdgcn_sched_barrier(0);
        __builtin_amdgcn_s_barrier();
    }
#undef STAGE_A
#undef STAGE_B

    // epilogue: C/D layout col=lane&15, row=(lane>>4)*4+reg; quadrant remap
#pragma unroll
    for (int nt = 0; nt < 4; nt++) {
        const int col = n0 + ((nt < 2) ? (wc * 32 + nt * 16) : (128 + wc * 32 + (nt - 2) * 16)) + lr;
        const float bv = bias[col];
#pragma unroll
        for (int mt = 0; mt < 8; mt++) {
            const int rbase = m0 + ((mt < 4) ? (wr * 64 + mt * 16) : (128 + wr * 64 + (mt - 4) * 16)) + lg * 4;
#pragma unroll
            for (int r = 0; r < 4; r++) {
                float v = acc[mt][nt][r] + bv;
                if (GELU) v = 0.5f * v * (1.f + erff(v * 0.70710678118654752f));
                outh[(size_t)(rbase + r) * N + col] = __float2bfloat16(v);
            }
        }
    }
}

// ---------------------------------------------------------------------------
// 128x128 GEMM (m97 structure) — kept for the low-N shapes (O-proj, PR) where
// 256^2 tiling would idle most CUs (96 blocks on 256 CUs).
// ---------------------------------------------------------------------------
template <bool RES, bool GELU, bool WF, bool WH>
__global__ __launch_bounds__(256) void gemm_bt(const __hip_bfloat16* __restrict__ A,
                                               const __hip_bfloat16* __restrict__ Bt,
                                               const float* __restrict__ bias,
                                               const float* __restrict__ res,
                                               float* __restrict__ outf,
                                               __hip_bfloat16* __restrict__ outh,
                                               int N, int K) {
    __shared__ __hip_bfloat16 lA0[128 * 32], lA1[128 * 32];
    __shared__ __hip_bfloat16 lB0[128 * 32], lB1[128 * 32];
    const int t = threadIdx.x;
    const int w = t >> 6, l = t & 63;
    const int lr = l & 15, lg = l >> 4;
    const int bid = blockIdx.x;
    const int xcd = bid & 7;
    const int local = bid >> 3;
    const int m0 = (xcd * 8 + (local & 7)) * 128;
    const int n0 = (local >> 3) * 128;
    const int wm = (w & 1) * 64, wn = (w >> 1) * 64;

    f32x4 acc[4][4];
#pragma unroll
    for (int i = 0; i < 4; i++)
#pragma unroll
        for (int j = 0; j < 4; j++) acc[i][j] = (f32x4){0.f, 0.f, 0.f, 0.f};

    for (int k0 = 0; k0 < K; k0 += 64) {
        __syncthreads();
#pragma unroll
        for (int i = 0; i < 2; i++) {
            int c = t + i * 256;            // 512 chunks of 16B per 8KB tile
            int row = c >> 2, seg = c & 3;  // row-major [128][32] bf16
            const size_t ab = (size_t)(m0 + row) * K + k0 + seg * 8;
            const size_t bb = (size_t)(n0 + row) * K + k0 + seg * 8;
            gld_lds16(&A[ab],       &lA0[c * 8]);
            gld_lds16(&A[ab + 32],  &lA1[c * 8]);
            gld_lds16(&Bt[bb],      &lB0[c * 8]);
            gld_lds16(&Bt[bb + 32], &lB1[c * 8]);
        }
        __syncthreads();
#pragma unroll
        for (int hh = 0; hh < 2; hh++) {
            const __hip_bfloat16* sA = hh ? lA1 : lA0;
            const __hip_bfloat16* sB = hh ? lB1 : lB0;
            bf16x8 af[4], bfr[4];
#pragma unroll
            for (int mt = 0; mt < 4; mt++)
                af[mt] = *(const bf16x8*)&sA[(wm + mt * 16 + lr) * 32 + lg * 8];
#pragma unroll
            for (int nt = 0; nt < 4; nt++)
                bfr[nt] = *(const bf16x8*)&sB[(wn + nt * 16 + lr) * 32 + lg * 8];
#pragma unroll
            for (int mt = 0; mt < 4; mt++)
#pragma unroll
                for (int nt = 0; nt < 4; nt++)
                    acc[mt][nt] = MFMA16(af[mt], bfr[nt], acc[mt][nt]);
        }
    }

#pragma unroll
    for (int nt = 0; nt < 4; nt++) {
        const int col = n0 + wn + nt * 16 + lr;
        const float bv = bias[col];
#pragma unroll
        for (int mt = 0; mt < 4; mt++) {
#pragma unroll
            for (int r = 0; r < 4; r++) {
                const int row = m0 + wm + mt * 16 + lg * 4 + r;
                const size_t idx = (size_t)row * N + col;
                float v = acc[mt][nt][r] + bv;
                if (RES) v += res[idx];
                if (GELU) v = 0.5f * v * (1.f + erff(v * 0.70710678118654752f));
                if (WF) outf[idx] = v;
                if (WH) outh[idx] = __float2bfloat16(v);
            }
        }
    }
}

// ---------------------------------------------------------------------------
// LayerNorm over W=768: one WAVE per row (4 rows/block), float4 loads, no LDS.
// ---------------------------------------------------------------------------
__global__ __launch_bounds__(256) void ln_kernel(const float* __restrict__ h,
                                                 const float* __restrict__ g,
                                                 const float* __restrict__ b,
                                                 __hip_bfloat16* __restrict__ y) {
    const int t = threadIdx.x;
    const int w = t >> 6, l = t & 63;
    const int row = blockIdx.x * 4 + w;
    const float4* hr = (const float4*)(h + (size_t)row * 768);
    const float4* g4 = (const float4*)g;
    const float4* b4 = (const float4*)b;
    float4 x[3];
    float s = 0.f, q = 0.f;
#pragma unroll
    for (int j = 0; j < 3; j++) {
        x[j] = hr[l + j * 64];
        s += x[j].x + x[j].y + x[j].z + x[j].w;
        q += x[j].x * x[j].x + x[j].y * x[j].y + x[j].z * x[j].z + x[j].w * x[j].w;
    }
#pragma unroll
    for (int d = 1; d < 64; d <<= 1) {
        s += __shfl_xor(s, d);
        q += __shfl_xor(q, d);
    }
    const float mean = s * (1.f / 768.f);
    const float var = q * (1.f / 768.f) - mean * mean;
    const float rs = rsqrtf(var + 1e-5f);
    uint2* yr = (uint2*)(y + (size_t)row * 768);
#pragma unroll
    for (int j = 0; j < 3; j++) {
        const float4 gg = g4[l + j * 64], bb = b4[l + j * 64];
        float o0 = (x[j].x - mean) * rs * gg.x + bb.x;
        float o1 = (x[j].y - mean) * rs * gg.y + bb.y;
        float o2 = (x[j].z - mean) * rs * gg.z + bb.z;
        float o3 = (x[j].w - mean) * rs * gg.w + bb.w;
        yr[l + j * 64] = make_uint2(pack_bf2(o0, o1), pack_bf2(o2, o3));
    }
}

// ---------------------------------------------------------------------------
// Per-layer weight transpose+convert: W[K,N] fp32 -> Wt[N,K] bf16 (4 matrices).
// ---------------------------------------------------------------------------
__global__ __launch_bounds__(256) void transpose_weights(const float* __restrict__ sq,
                                                         const float* __restrict__ so,
                                                         const float* __restrict__ sf,
                                                         const float* __restrict__ sp,
                                                         __hip_bfloat16* __restrict__ dq,
                                                         __hip_bfloat16* __restrict__ dO,
                                                         __hip_bfloat16* __restrict__ df,
                                                         __hip_bfloat16* __restrict__ dp) {
    const int bid = blockIdx.x;
    const float* src;
    __hip_bfloat16* dst;
    int K, N, tloc;
    if (bid < 1728)      { src = sq; dst = dq; K = 768;  N = 2304; tloc = bid; }
    else if (bid < 2304) { src = so; dst = dO; K = 768;  N = 768;  tloc = bid - 1728; }
    else if (bid < 4608) { src = sf; dst = df; K = 768;  N = 3072; tloc = bid - 2304; }
    else                 { src = sp; dst = dp; K = 3072; N = 768;  tloc = bid - 4608; }
    const int ktiles = K / 32;
    const int k0 = (tloc % ktiles) * 32;
    const int n0 = (tloc / ktiles) * 32;
    const int t = threadIdx.x;
    __shared__ float tile[32][33];
#pragma unroll
    for (int p = 0; p < 4; p++) {
        int rr = p * 8 + (t >> 5);
        tile[rr][t & 31] = src[(size_t)(k0 + rr) * N + n0 + (t & 31)];
    }
    __syncthreads();
#pragma unroll
    for (int p = 0; p < 4; p++) {
        int rr = p * 8 + (t >> 5);
        dst[(size_t)(n0 + rr) * K + k0 + (t & 31)] = __float2bfloat16(tile[t & 31][rr]);
    }
}

// ---------------------------------------------------------------------------
// V transpose: qkv[b,n, h*192+128+c] -> vt[(b*12+h)*64+c, n]   (bf16 bits)
// ---------------------------------------------------------------------------
__global__ __launch_bounds__(256) void vt_transpose(const short* __restrict__ qkv,
                                                    short* __restrict__ vt) {
    const int bid = blockIdx.x;           // 96 bh * 64 tiles
    const int bh = bid >> 6, tau = bid & 63;
    const int b = bh / 12, h = bh % 12;
    const int ct = tau >> 5, nt = tau & 31;
    const int n0 = nt * 32, c0 = ct * 32;
    const int t = threadIdx.x;
    __shared__ short tile[32][33];
    const short* base = qkv + (size_t)(b * 1024 + n0) * 2304 + h * 192 + 128 + c0;
#pragma unroll
    for (int p = 0; p < 4; p++) {
        int rr = p * 8 + (t >> 5);
        tile[rr][t & 31] = base[(size_t)rr * 2304 + (t & 31)];
    }
    __syncthreads();
    short* ob = vt + (size_t)((b * 12 + h) * 64 + c0) * 1024 + n0;
#pragma unroll
    for (int p = 0; p < 4; p++) {
        int rr = p * 8 + (t >> 5);
        ob[(size_t)rr * 1024 + (t & 31)] = tile[t & 31][rr];
    }
}

// ---------------------------------------------------------------------------
// Flash attention, S^T formulation (round-0 version: swizzled gld_lds staging,
// cvt_pk packing, defer-max).  Workgroup = (64 queries, head, batch).
// ---------------------------------------------------------------------------
__global__ __launch_bounds__(256) void attn_kernel(const short* __restrict__ qkv,
                                                   const short* __restrict__ vt,
                                                   short* __restrict__ attnout) {
    const int bid = blockIdx.x;           // 1536
    const int xcd = bid & 7, j = bid >> 3;
    const int bh = xcd * 12 + (j >> 4);
    const int qt = j & 15;
    const int b = bh / 12, hh = bh % 12;
    const int t = threadIdx.x, w = t >> 6, l = t & 63;
    const int lr = l & 15, lg = l >> 4;
    const int x7 = lr & 7;
    __shared__ short lK[64 * 64];          // [key][dim], linear, XOR-swizzled content
    __shared__ short lV[64 * 64];          // [dim][key], linear, XOR-swizzled content
    __shared__ short lP[4][16 * 64];       // per-wave P, [q][key], XOR-swizzled
    const int qw = qt * 64 + w * 16;

    bf16x8 bq[2];
#pragma unroll
    for (int ks = 0; ks < 2; ks++)
        bq[ks] = *(const bf16x8*)&qkv[(size_t)(b * 1024 + qw + lr) * 2304 + hh * 192 + ks * 32 + lg * 8];

    int col[2];
    col[0] = (lg ^ x7) * 8;
    col[1] = ((4 | lg) ^ x7) * 8;

    const int c0 = t, c1 = t + 256;
    const int r0 = c0 >> 3, r1 = c1 >> 3;
    const int s0 = (c0 & 7) ^ (r0 & 7), s1 = (c1 & 7) ^ (r1 & 7);
    const short* gK0 = qkv + (size_t)(b * 1024 + r0) * 2304 + hh * 192 + 64 + s0 * 8;
    const short* gK1 = qkv + (size_t)(b * 1024 + r1) * 2304 + hh * 192 + 64 + s1 * 8;
    const short* gV0 = vt + (size_t)((b * 12 + hh) * 64 + r0) * 1024 + s0 * 8;
    const short* gV1 = vt + (size_t)((b * 12 + hh) * 64 + r1) * 1024 + s1 * 8;

    f32x4 o[4];
#pragma unroll
    for (int dt = 0; dt < 4; dt++) o[dt] = (f32x4){0.f, 0.f, 0.f, 0.f};
    const float cexp = 0.125f * 1.44269504088896f;  // scale^2 * log2(e)
    float cm = -1.0e30f;   // running c*max, per-lane query q=lr
    float lsum = 0.f;

    for (int kt = 0; kt < 16; kt++) {
        const int key0 = kt * 64;
        __syncthreads();
        gld_lds16(gK0 + (size_t)key0 * 2304, &lK[c0 * 8]);
        gld_lds16(gK1 + (size_t)key0 * 2304, &lK[c1 * 8]);
        gld_lds16(gV0 + key0, &lV[c0 * 8]);
        gld_lds16(gV1 + key0, &lV[c1 * 8]);
        __syncthreads();   // compiler drains vmcnt before s_barrier

        f32x4 s[4];
#pragma unroll
        for (int nt = 0; nt < 4; nt++) s[nt] = (f32x4){0.f, 0.f, 0.f, 0.f};
#pragma unroll
        for (int nt = 0; nt < 4; nt++)
#pragma unroll
            for (int ks = 0; ks < 2; ks++) {
                bf16x8 ak = *(const bf16x8*)&lK[(nt * 16 + lr) * 64 + col[ks]];
                s[nt] = MFMA16(ak, bq[ks], s[nt]);
            }

        float mx = s[0][0];
#pragma unroll
        for (int nt = 0; nt < 4; nt++)
#pragma unroll
            for (int r = 0; r < 4; r++) mx = fmaxf(mx, s[nt][r]);
        mx = fmaxf(mx, __shfl_xor(mx, 16));
        mx = fmaxf(mx, __shfl_xor(mx, 32));
        const float tm = mx * cexp;
        if (!__all(tm <= cm + 8.f)) {
            const float cmn = fmaxf(cm, tm);
            const float alpha = exp2f(cm - cmn);   // first tile: exp2(-inf)=0
            cm = cmn;
            lsum *= alpha;
            float af[4];
#pragma unroll
            for (int r = 0; r < 4; r++) af[r] = __shfl(alpha, lg * 4 + r);
#pragma unroll
            for (int dt = 0; dt < 4; dt++)
#pragma unroll
                for (int r = 0; r < 4; r++) o[dt][r] *= af[r];
        }
        float ps = 0.f;
#pragma unroll
        for (int nt = 0; nt < 4; nt++)
#pragma unroll
            for (int r = 0; r < 4; r++) {
                float p = exp2f(s[nt][r] * cexp - cm);   // bounded by 2^8
                s[nt][r] = p;
                ps += p;
            }
        ps += __shfl_xor(ps, 16);
        ps += __shfl_xor(ps, 32);
        lsum += ps;

#pragma unroll
        for (int nt = 0; nt < 4; nt++) {
            unsigned pk0 = cvt_pk_bf16(s[nt][0], s[nt][1]);
            unsigned pk1 = cvt_pk_bf16(s[nt][2], s[nt][3]);
            const int S = nt * 2 + (lg >> 1);
            *(uint2*)&lP[w][lr * 64 + ((S ^ x7) << 3) + ((lg & 1) << 2)] = make_uint2(pk0, pk1);
        }

#pragma unroll
        for (int kc = 0; kc < 2; kc++) {
            bf16x8 ap = *(const bf16x8*)&lP[w][lr * 64 + col[kc]];
#pragma unroll
            for (int dt = 0; dt < 4; dt++) {
                bf16x8 bv = *(const bf16x8*)&lV[(dt * 16 + lr) * 64 + col[kc]];
                o[dt] = MFMA16(ap, bv, o[dt]);
            }
        }
    }

    float inv[4];
#pragma unroll
    for (int r = 0; r < 4; r++) inv[r] = 1.f / __shfl(lsum, lg * 4 + r);
#pragma unroll
    for (int dt = 0; dt < 4; dt++)
#pragma unroll
        for (int r = 0; r < 4; r++)
            attnout[(size_t)(b * 1024 + qw + lg * 4 + r) * 768 + hh * 64 + dt * 16 + lr] =
                (short)f32_to_bf16_bits(o[dt][r] * inv[r]);
}

// ---------------------------------------------------------------------------
// Host
// ---------------------------------------------------------------------------
extern "C" void kernel_launch(void* const* d_in, const int* in_sizes, int n_in,
                              void* d_out, int out_size, void* d_ws, size_t ws_size,
                              hipStream_t stream) {
    const float* x    = (const float*)d_in[0];
    const float* Wqkv = (const float*)d_in[1];
    const float* bqkv = (const float*)d_in[2];
    const float* Wo   = (const float*)d_in[3];
    const float* bo   = (const float*)d_in[4];
    const float* Wfc  = (const float*)d_in[5];
    const float* bfc  = (const float*)d_in[6];
    const float* Wpr  = (const float*)d_in[7];
    const float* bpr  = (const float*)d_in[8];
    const float* g1   = (const float*)d_in[9];
    const float* b1   = (const float*)d_in[10];
    const float* g2   = (const float*)d_in[11];
    const float* b2   = (const float*)d_in[12];
    float* h = (float*)d_out;   // h lives in d_out throughout

    char* ws = (char*)d_ws;
    size_t off = 0;
    auto alloc = [&](size_t bytes) -> void* {
        void* p = ws + off;
        off += (bytes + 255) & ~(size_t)255;
        return p;
    };
    __hip_bfloat16* tQKV = (__hip_bfloat16*)alloc((size_t)2304 * 768 * 2);
    __hip_bfloat16* tO   = (__hip_bfloat16*)alloc((size_t)768 * 768 * 2);
    __hip_bfloat16* tFC  = (__hip_bfloat16*)alloc((size_t)3072 * 768 * 2);
    __hip_bfloat16* tPR  = (__hip_bfloat16*)alloc((size_t)768 * 3072 * 2);
    __hip_bfloat16* y    = (__hip_bfloat16*)alloc((size_t)8192 * 768 * 2);
    __hip_bfloat16* att  = (__hip_bfloat16*)alloc((size_t)8192 * 768 * 2);
    __hip_bfloat16* vtb  = (__hip_bfloat16*)alloc((size_t)8192 * 768 * 2);
    __hip_bfloat16* big  = (__hip_bfloat16*)alloc((size_t)8192 * 3072 * 2); // qkv & fc share
    __hip_bfloat16* qkvb = big;
    __hip_bfloat16* fcb  = big;

    hipMemcpyAsync(h, x, (size_t)8 * 1024 * 768 * 4, hipMemcpyDeviceToDevice, stream);

    for (int L = 0; L < 8; L++) {
        const float* wq = Wqkv + (size_t)L * 768 * 2304;
        const float* wo = Wo   + (size_t)L * 768 * 768;
        const float* wf = Wfc  + (size_t)L * 768 * 3072;
        const float* wp = Wpr  + (size_t)L * 3072 * 768;

        transpose_weights<<<6912, 256, 0, stream>>>(wq, wo, wf, wp, tQKV, tO, tFC, tPR);

        ln_kernel<<<2048, 256, 0, stream>>>(h, g1 + L * 768, b1 + L * 768, y);

        // QKV: M=8192, N=2304, K=768 -> 32 x 9 = 288 blocks (8-phase 256^2)
        gemm256<false><<<288, 512, 0, stream>>>(y, tQKV, bqkv + L * 2304, qkvb, 2304, 768);

        vt_transpose<<<6144, 256, 0, stream>>>((const short*)qkvb, (short*)vtb);

        attn_kernel<<<1536, 256, 0, stream>>>(
            (const short*)qkvb, (const short*)vtb, (short*)att);

        gemm_bt<true, false, true, false><<<6 * 64, 256, 0, stream>>>(
            att, tO, bo + L * 768, h, h, nullptr, 768, 768);

        ln_kernel<<<2048, 256, 0, stream>>>(h, g2 + L * 768, b2 + L * 768, y);

        // FC: M=8192, N=3072, K=768 -> 32 x 12 = 384 blocks (8-phase 256^2)
        gemm256<true><<<384, 512, 0, stream>>>(y, tFC, bfc + L * 3072, fcb, 3072, 768);

        gemm_bt<true, false, true, false><<<6 * 64, 256, 0, stream>>>(
            fcb, tPR, bpr + L * 768, h, h, nullptr, 768, 3072);
    }
}

// Round 4
// 2390.768 us; speedup vs baseline: 1.0846x; 1.0812x over previous
//
#include <hip/hip_runtime.h>
#include <hip/hip_bf16.h>
#include <cstdint>
#include <cstddef>

// ---------------------------------------------------------------------------
// Transformer: L=8, B=8, N=1024, W=768, H=12, C=64.  h kept fp32 in d_out.
// All GEMMs bf16-MFMA (16x16x32), fp32 accum. LN/softmax/GELU fp32.
// ---------------------------------------------------------------------------

typedef __attribute__((ext_vector_type(8))) short bf16x8;   // 8 bf16 = 4 VGPRs
typedef __attribute__((ext_vector_type(4))) float f32x4;

#define MFMA16(a, b, c) __builtin_amdgcn_mfma_f32_16x16x32_bf16((a), (b), (c), 0, 0, 0)

__device__ __forceinline__ void gld_lds16(const void* g, void* l) {
    // async global->LDS, 16B per lane; LDS dest must be uniform_base + lane*16
    __builtin_amdgcn_global_load_lds((const __attribute__((address_space(1))) unsigned int*)g,
                                     (__attribute__((address_space(3))) unsigned int*)l,
                                     16, 0, 0);
}

__device__ __forceinline__ unsigned short f32_to_bf16_bits(float f) {
    unsigned u = __builtin_bit_cast(unsigned, f);
    u += 0x7fffu + ((u >> 16) & 1u);      // RNE; inputs are finite
    return (unsigned short)(u >> 16);
}

__device__ __forceinline__ unsigned pack_bf2(float a, float b) {
    return (unsigned)f32_to_bf16_bits(a) | ((unsigned)f32_to_bf16_bits(b) << 16);
}

__device__ __forceinline__ unsigned cvt_pk_bf16(float lo, float hi) {
    // dst = { [15:0]=bf16(lo), [31:16]=bf16(hi) }, RNE — same as pack_bf2
    unsigned r;
    asm("v_cvt_pk_bf16_f32 %0, %1, %2" : "=v"(r) : "v"(lo), "v"(hi));
    return r;
}

// ---------------------------------------------------------------------------
// 128x128 GEMM, 2-phase DOUBLE-BUFFERED (T3-minimum recipe):
//   prologue: STAGE(buf0, 0); barrier
//   kt loop:  STAGE(buf^1, kt+1) issued FIRST; ds_read frags from buf;
//             32 MFMA; ONE __syncthreads() (vmcnt0+lgkm0+barrier) per kt.
// Stage latency is covered by the frag reads + MFMA of the current tile
// (the old kernel had issue->drain back-to-back: zero cover).
// LDS [2][128][64] bf16 x (A,B) = 64 KiB -> 2 blocks/CU.
// XOR-8 swizzle on per-lane GLOBAL source (slot'=slot^(row&7)), linear
// gld_lds dest, same XOR on ds_read_b128 -> 0 bank conflicts (verified r2/r3).
// C[M,N] = A[M,K](bf16) @ Bt[N,K]^T(bf16) + bias; optional residual(fp32,
// in-place ok), exact GELU, fp32/bf16 outputs.  M==8192 (64 m-tiles),
// N%128==0, K%64==0.  Grid = 64*(N/128), XCD-swizzled.
// ---------------------------------------------------------------------------
template <bool RES, bool GELU, bool WF, bool WH>
__global__ __launch_bounds__(256, 2) void gemm_bt(const __hip_bfloat16* __restrict__ A,
                                                  const __hip_bfloat16* __restrict__ Bt,
                                                  const float* __restrict__ bias,
                                                  const float* __restrict__ res,
                                                  float* __restrict__ outf,
                                                  __hip_bfloat16* __restrict__ outh,
                                                  int N, int K) {
    __shared__ __hip_bfloat16 lA[2][128 * 64];
    __shared__ __hip_bfloat16 lB[2][128 * 64];
    const int t = threadIdx.x;
    const int w = t >> 6, l = t & 63;
    const int lr = l & 15, lg = l >> 4;
    const int x7 = lr & 7;
    const int cs0 = (lg ^ x7) << 3;        // swizzled col offset (elems), ks=0
    const int cs1 = ((4 | lg) ^ x7) << 3;  // swizzled col offset (elems), ks=1
    // XCD-aware decode: 64 m-tiles total, 8 per XCD
    const int bid = blockIdx.x;
    const int xcd = bid & 7;
    const int local = bid >> 3;
    const int m0 = (xcd * 8 + (local & 7)) * 128;
    const int n0 = (local >> 3) * 128;
    const int wm = (w & 1) * 64, wn = (w >> 1) * 64;

    // staging: tile [128][64] = 1024 chunks of 16B; thread owns c = t + j*256.
    // chunk c: row = c>>3, phys slot = c&7; global col = (slot^(row&7))*8.
    const int srow = t >> 3, sslot = t & 7;       // row&7 == srow&7 (j*32 mult of 8)
    const int sx = (sslot ^ (srow & 7)) << 3;

    f32x4 acc[4][4];
#pragma unroll
    for (int i = 0; i < 4; i++)
#pragma unroll
        for (int j = 0; j < 4; j++) acc[i][j] = (f32x4){0.f, 0.f, 0.f, 0.f};

#define STAGE(buf, kt)                                                        \
    {                                                                         \
        _Pragma("unroll") for (int j = 0; j < 4; j++) {                       \
            const int row = srow + j * 32;                                    \
            const int gcol = (kt) * 64 + sx;                                  \
            gld_lds16(&A[(size_t)(m0 + row) * K + gcol], &lA[buf][(t + j * 256) * 8]); \
            gld_lds16(&Bt[(size_t)(n0 + row) * K + gcol], &lB[buf][(t + j * 256) * 8]); \
        }                                                                     \
    }

    // prologue: stage K-tile 0 into buf0
    STAGE(0, 0);
    __syncthreads();

    const int NT = K >> 6;
    for (int kt = 0; kt < NT; ++kt) {
        const int cur = kt & 1;
        if (kt + 1 < NT) STAGE(cur ^ 1, kt + 1);   // prefetch issued FIRST
        const __hip_bfloat16* sA = lA[cur];
        const __hip_bfloat16* sB = lB[cur];
        bf16x8 af[4][2], bf[4][2];
#pragma unroll
        for (int mt = 0; mt < 4; mt++) {
            const int ro = (wm + mt * 16 + lr) * 64;
            af[mt][0] = *(const bf16x8*)&sA[ro + cs0];
            af[mt][1] = *(const bf16x8*)&sA[ro + cs1];
        }
#pragma unroll
        for (int nt = 0; nt < 4; nt++) {
            const int ro = (wn + nt * 16 + lr) * 64;
            bf[nt][0] = *(const bf16x8*)&sB[ro + cs0];
            bf[nt][1] = *(const bf16x8*)&sB[ro + cs1];
        }
#pragma unroll
        for (int mt = 0; mt < 4; mt++)
#pragma unroll
            for (int nt = 0; nt < 4; nt++) {
                acc[mt][nt] = MFMA16(af[mt][0], bf[nt][0], acc[mt][nt]);
                acc[mt][nt] = MFMA16(af[mt][1], bf[nt][1], acc[mt][nt]);
            }
        __syncthreads();   // single drain+barrier per K-tile (covers stage)
    }
#undef STAGE

    // epilogue: C/D layout col=lane&15, row=(lane>>4)*4+reg  [m89/m91 verified]
#pragma unroll
    for (int nt = 0; nt < 4; nt++) {
        const int col = n0 + wn + nt * 16 + lr;
        const float bv = bias[col];
#pragma unroll
        for (int mt = 0; mt < 4; mt++) {
#pragma unroll
            for (int r = 0; r < 4; r++) {
                const int row = m0 + wm + mt * 16 + lg * 4 + r;
                const size_t idx = (size_t)row * N + col;
                float v = acc[mt][nt][r] + bv;
                if (RES) v += res[idx];
                if (GELU) v = 0.5f * v * (1.f + erff(v * 0.70710678118654752f));
                if (WF) outf[idx] = v;
                if (WH) outh[idx] = __float2bfloat16(v);
            }
        }
    }
}

// ---------------------------------------------------------------------------
// LayerNorm over W=768: one WAVE per row (4 rows/block), float4 loads, no LDS.
// ---------------------------------------------------------------------------
__global__ __launch_bounds__(256) void ln_kernel(const float* __restrict__ h,
                                                 const float* __restrict__ g,
                                                 const float* __restrict__ b,
                                                 __hip_bfloat16* __restrict__ y) {
    const int t = threadIdx.x;
    const int w = t >> 6, l = t & 63;
    const int row = blockIdx.x * 4 + w;
    const float4* hr = (const float4*)(h + (size_t)row * 768);
    const float4* g4 = (const float4*)g;
    const float4* b4 = (const float4*)b;
    float4 x[3];
    float s = 0.f, q = 0.f;
#pragma unroll
    for (int j = 0; j < 3; j++) {
        x[j] = hr[l + j * 64];
        s += x[j].x + x[j].y + x[j].z + x[j].w;
        q += x[j].x * x[j].x + x[j].y * x[j].y + x[j].z * x[j].z + x[j].w * x[j].w;
    }
#pragma unroll
    for (int d = 1; d < 64; d <<= 1) {
        s += __shfl_xor(s, d);
        q += __shfl_xor(q, d);
    }
    const float mean = s * (1.f / 768.f);
    const float var = q * (1.f / 768.f) - mean * mean;
    const float rs = rsqrtf(var + 1e-5f);
    uint2* yr = (uint2*)(y + (size_t)row * 768);
#pragma unroll
    for (int j = 0; j < 3; j++) {
        const float4 gg = g4[l + j * 64], bb = b4[l + j * 64];
        float o0 = (x[j].x - mean) * rs * gg.x + bb.x;
        float o1 = (x[j].y - mean) * rs * gg.y + bb.y;
        float o2 = (x[j].z - mean) * rs * gg.z + bb.z;
        float o3 = (x[j].w - mean) * rs * gg.w + bb.w;
        yr[l + j * 64] = make_uint2(pack_bf2(o0, o1), pack_bf2(o2, o3));
    }
}

// ---------------------------------------------------------------------------
// Per-layer weight transpose+convert: W[K,N] fp32 -> Wt[N,K] bf16 (4 matrices).
// ---------------------------------------------------------------------------
__global__ __launch_bounds__(256) void transpose_weights(const float* __restrict__ sq,
                                                         const float* __restrict__ so,
                                                         const float* __restrict__ sf,
                                                         const float* __restrict__ sp,
                                                         __hip_bfloat16* __restrict__ dq,
                                                         __hip_bfloat16* __restrict__ dO,
                                                         __hip_bfloat16* __restrict__ df,
                                                         __hip_bfloat16* __restrict__ dp) {
    const int bid = blockIdx.x;
    const float* src;
    __hip_bfloat16* dst;
    int K, N, tloc;
    if (bid < 1728)      { src = sq; dst = dq; K = 768;  N = 2304; tloc = bid; }
    else if (bid < 2304) { src = so; dst = dO; K = 768;  N = 768;  tloc = bid - 1728; }
    else if (bid < 4608) { src = sf; dst = df; K = 768;  N = 3072; tloc = bid - 2304; }
    else                 { src = sp; dst = dp; K = 3072; N = 768;  tloc = bid - 4608; }
    const int ktiles = K / 32;
    const int k0 = (tloc % ktiles) * 32;
    const int n0 = (tloc / ktiles) * 32;
    const int t = threadIdx.x;
    __shared__ float tile[32][33];
#pragma unroll
    for (int p = 0; p < 4; p++) {
        int rr = p * 8 + (t >> 5);
        tile[rr][t & 31] = src[(size_t)(k0 + rr) * N + n0 + (t & 31)];
    }
    __syncthreads();
#pragma unroll
    for (int p = 0; p < 4; p++) {
        int rr = p * 8 + (t >> 5);
        dst[(size_t)(n0 + rr) * K + k0 + (t & 31)] = __float2bfloat16(tile[t & 31][rr]);
    }
}

// ---------------------------------------------------------------------------
// V transpose: qkv[b,n, h*192+128+c] -> vt[(b*12+h)*64+c, n]   (bf16 bits)
// ---------------------------------------------------------------------------
__global__ __launch_bounds__(256) void vt_transpose(const short* __restrict__ qkv,
                                                    short* __restrict__ vt) {
    const int bid = blockIdx.x;           // 96 bh * 64 tiles
    const int bh = bid >> 6, tau = bid & 63;
    const int b = bh / 12, h = bh % 12;
    const int ct = tau >> 5, nt = tau & 31;
    const int n0 = nt * 32, c0 = ct * 32;
    const int t = threadIdx.x;
    __shared__ short tile[32][33];
    const short* base = qkv + (size_t)(b * 1024 + n0) * 2304 + h * 192 + 128 + c0;
#pragma unroll
    for (int p = 0; p < 4; p++) {
        int rr = p * 8 + (t >> 5);
        tile[rr][t & 31] = base[(size_t)rr * 2304 + (t & 31)];
    }
    __syncthreads();
    short* ob = vt + (size_t)((b * 12 + h) * 64 + c0) * 1024 + n0;
#pragma unroll
    for (int p = 0; p < 4; p++) {
        int rr = p * 8 + (t >> 5);
        ob[(size_t)rr * 1024 + (t & 31)] = tile[t & 31][rr];
    }
}

// ---------------------------------------------------------------------------
// Flash attention, S^T formulation (swizzled gld_lds staging, cvt_pk packing,
// defer-max).  Workgroup = (64 queries, head, batch).
// ---------------------------------------------------------------------------
__global__ __launch_bounds__(256) void attn_kernel(const short* __restrict__ qkv,
                                                   const short* __restrict__ vt,
                                                   short* __restrict__ attnout) {
    const int bid = blockIdx.x;           // 1536
    const int xcd = bid & 7, j = bid >> 3;
    const int bh = xcd * 12 + (j >> 4);
    const int qt = j & 15;
    const int b = bh / 12, hh = bh % 12;
    const int t = threadIdx.x, w = t >> 6, l = t & 63;
    const int lr = l & 15, lg = l >> 4;
    const int x7 = lr & 7;
    __shared__ short lK[64 * 64];          // [key][dim], linear, XOR-swizzled content
    __shared__ short lV[64 * 64];          // [dim][key], linear, XOR-swizzled content
    __shared__ short lP[4][16 * 64];       // per-wave P, [q][key], XOR-swizzled
    const int qw = qt * 64 + w * 16;

    bf16x8 bq[2];
#pragma unroll
    for (int ks = 0; ks < 2; ks++)
        bq[ks] = *(const bf16x8*)&qkv[(size_t)(b * 1024 + qw + lr) * 2304 + hh * 192 + ks * 32 + lg * 8];

    int col[2];
    col[0] = (lg ^ x7) * 8;
    col[1] = ((4 | lg) ^ x7) * 8;

    const int c0 = t, c1 = t + 256;
    const int r0 = c0 >> 3, r1 = c1 >> 3;
    const int s0 = (c0 & 7) ^ (r0 & 7), s1 = (c1 & 7) ^ (r1 & 7);
    const short* gK0 = qkv + (size_t)(b * 1024 + r0) * 2304 + hh * 192 + 64 + s0 * 8;
    const short* gK1 = qkv + (size_t)(b * 1024 + r1) * 2304 + hh * 192 + 64 + s1 * 8;
    const short* gV0 = vt + (size_t)((b * 12 + hh) * 64 + r0) * 1024 + s0 * 8;
    const short* gV1 = vt + (size_t)((b * 12 + hh) * 64 + r1) * 1024 + s1 * 8;

    f32x4 o[4];
#pragma unroll
    for (int dt = 0; dt < 4; dt++) o[dt] = (f32x4){0.f, 0.f, 0.f, 0.f};
    const float cexp = 0.125f * 1.44269504088896f;  // scale^2 * log2(e)
    float cm = -1.0e30f;   // running c*max, per-lane query q=lr
    float lsum = 0.f;

    for (int kt = 0; kt < 16; kt++) {
        const int key0 = kt * 64;
        __syncthreads();
        gld_lds16(gK0 + (size_t)key0 * 2304, &lK[c0 * 8]);
        gld_lds16(gK1 + (size_t)key0 * 2304, &lK[c1 * 8]);
        gld_lds16(gV0 + key0, &lV[c0 * 8]);
        gld_lds16(gV1 + key0, &lV[c1 * 8]);
        __syncthreads();   // compiler drains vmcnt before s_barrier

        f32x4 s[4];
#pragma unroll
        for (int nt = 0; nt < 4; nt++) s[nt] = (f32x4){0.f, 0.f, 0.f, 0.f};
#pragma unroll
        for (int nt = 0; nt < 4; nt++)
#pragma unroll
            for (int ks = 0; ks < 2; ks++) {
                bf16x8 ak = *(const bf16x8*)&lK[(nt * 16 + lr) * 64 + col[ks]];
                s[nt] = MFMA16(ak, bq[ks], s[nt]);
            }

        float mx = s[0][0];
#pragma unroll
        for (int nt = 0; nt < 4; nt++)
#pragma unroll
            for (int r = 0; r < 4; r++) mx = fmaxf(mx, s[nt][r]);
        mx = fmaxf(mx, __shfl_xor(mx, 16));
        mx = fmaxf(mx, __shfl_xor(mx, 32));
        const float tm = mx * cexp;
        if (!__all(tm <= cm + 8.f)) {
            const float cmn = fmaxf(cm, tm);
            const float alpha = exp2f(cm - cmn);   // first tile: exp2(-inf)=0
            cm = cmn;
            lsum *= alpha;
            float af[4];
#pragma unroll
            for (int r = 0; r < 4; r++) af[r] = __shfl(alpha, lg * 4 + r);
#pragma unroll
            for (int dt = 0; dt < 4; dt++)
#pragma unroll
                for (int r = 0; r < 4; r++) o[dt][r] *= af[r];
        }
        float ps = 0.f;
#pragma unroll
        for (int nt = 0; nt < 4; nt++)
#pragma unroll
            for (int r = 0; r < 4; r++) {
                float p = exp2f(s[nt][r] * cexp - cm);   // bounded by 2^8
                s[nt][r] = p;
                ps += p;
            }
        ps += __shfl_xor(ps, 16);
        ps += __shfl_xor(ps, 32);
        lsum += ps;

#pragma unroll
        for (int nt = 0; nt < 4; nt++) {
            unsigned pk0 = cvt_pk_bf16(s[nt][0], s[nt][1]);
            unsigned pk1 = cvt_pk_bf16(s[nt][2], s[nt][3]);
            const int S = nt * 2 + (lg >> 1);
            *(uint2*)&lP[w][lr * 64 + ((S ^ x7) << 3) + ((lg & 1) << 2)] = make_uint2(pk0, pk1);
        }

#pragma unroll
        for (int kc = 0; kc < 2; kc++) {
            bf16x8 ap = *(const bf16x8*)&lP[w][lr * 64 + col[kc]];
#pragma unroll
            for (int dt = 0; dt < 4; dt++) {
                bf16x8 bv = *(const bf16x8*)&lV[(dt * 16 + lr) * 64 + col[kc]];
                o[dt] = MFMA16(ap, bv, o[dt]);
            }
        }
    }

    float inv[4];
#pragma unroll
    for (int r = 0; r < 4; r++) inv[r] = 1.f / __shfl(lsum, lg * 4 + r);
#pragma unroll
    for (int dt = 0; dt < 4; dt++)
#pragma unroll
        for (int r = 0; r < 4; r++)
            attnout[(size_t)(b * 1024 + qw + lg * 4 + r) * 768 + hh * 64 + dt * 16 + lr] =
                (short)f32_to_bf16_bits(o[dt][r] * inv[r]);
}

// ---------------------------------------------------------------------------
// Host
// ---------------------------------------------------------------------------
extern "C" void kernel_launch(void* const* d_in, const int* in_sizes, int n_in,
                              void* d_out, int out_size, void* d_ws, size_t ws_size,
                              hipStream_t stream) {
    const float* x    = (const float*)d_in[0];
    const float* Wqkv = (const float*)d_in[1];
    const float* bqkv = (const float*)d_in[2];
    const float* Wo   = (const float*)d_in[3];
    const float* bo   = (const float*)d_in[4];
    const float* Wfc  = (const float*)d_in[5];
    const float* bfc  = (const float*)d_in[6];
    const float* Wpr  = (const float*)d_in[7];
    const float* bpr  = (const float*)d_in[8];
    const float* g1   = (const float*)d_in[9];
    const float* b1   = (const float*)d_in[10];
    const float* g2   = (const float*)d_in[11];
    const float* b2   = (const float*)d_in[12];
    float* h = (float*)d_out;   // h lives in d_out throughout

    char* ws = (char*)d_ws;
    size_t off = 0;
    auto alloc = [&](size_t bytes) -> void* {
        void* p = ws + off;
        off += (bytes + 255) & ~(size_t)255;
        return p;
    };
    __hip_bfloat16* tQKV = (__hip_bfloat16*)alloc((size_t)2304 * 768 * 2);
    __hip_bfloat16* tO   = (__hip_bfloat16*)alloc((size_t)768 * 768 * 2);
    __hip_bfloat16* tFC  = (__hip_bfloat16*)alloc((size_t)3072 * 768 * 2);
    __hip_bfloat16* tPR  = (__hip_bfloat16*)alloc((size_t)768 * 3072 * 2);
    __hip_bfloat16* y    = (__hip_bfloat16*)alloc((size_t)8192 * 768 * 2);
    __hip_bfloat16* att  = (__hip_bfloat16*)alloc((size_t)8192 * 768 * 2);
    __hip_bfloat16* vtb  = (__hip_bfloat16*)alloc((size_t)8192 * 768 * 2);
    __hip_bfloat16* big  = (__hip_bfloat16*)alloc((size_t)8192 * 3072 * 2); // qkv & fc share
    __hip_bfloat16* qkvb = big;
    __hip_bfloat16* fcb  = big;

    hipMemcpyAsync(h, x, (size_t)8 * 1024 * 768 * 4, hipMemcpyDeviceToDevice, stream);

    for (int L = 0; L < 8; L++) {
        const float* wq = Wqkv + (size_t)L * 768 * 2304;
        const float* wo = Wo   + (size_t)L * 768 * 768;
        const float* wf = Wfc  + (size_t)L * 768 * 3072;
        const float* wp = Wpr  + (size_t)L * 3072 * 768;

        transpose_weights<<<6912, 256, 0, stream>>>(wq, wo, wf, wp, tQKV, tO, tFC, tPR);

        ln_kernel<<<2048, 256, 0, stream>>>(h, g1 + L * 768, b1 + L * 768, y);

        gemm_bt<false, false, false, true><<<18 * 64, 256, 0, stream>>>(
            y, tQKV, bqkv + L * 2304, nullptr, nullptr, qkvb, 2304, 768);

        vt_transpose<<<6144, 256, 0, stream>>>((const short*)qkvb, (short*)vtb);

        attn_kernel<<<1536, 256, 0, stream>>>(
            (const short*)qkvb, (const short*)vtb, (short*)att);

        gemm_bt<true, false, true, false><<<6 * 64, 256, 0, stream>>>(
            att, tO, bo + L * 768, h, h, nullptr, 768, 768);

        ln_kernel<<<2048, 256, 0, stream>>>(h, g2 + L * 768, b2 + L * 768, y);

        gemm_bt<false, true, false, true><<<24 * 64, 256, 0, stream>>>(
            y, tFC, bfc + L * 3072, nullptr, nullptr, fcb, 3072, 768);

        gemm_bt<true, false, true, false><<<6 * 64, 256, 0, stream>>>(
            fcb, tPR, bpr + L * 768, h, h, nullptr, 768, 3072);
    }
}

// Round 5
// 2197.762 us; speedup vs baseline: 1.1799x; 1.0878x over previous
//
#include <hip/hip_runtime.h>
#include <hip/hip_bf16.h>
#include <cstdint>
#include <cstddef>

// ---------------------------------------------------------------------------
// Transformer: L=8, B=8, N=1024, W=768, H=12, C=64.  h kept fp32 in d_out.
// All GEMMs bf16-MFMA (16x16x32), fp32 accum. LN/softmax/GELU fp32.
// ---------------------------------------------------------------------------

typedef __attribute__((ext_vector_type(8))) short bf16x8;   // 8 bf16 = 4 VGPRs
typedef __attribute__((ext_vector_type(4))) float f32x4;

#define MFMA16(a, b, c) __builtin_amdgcn_mfma_f32_16x16x32_bf16((a), (b), (c), 0, 0, 0)

__device__ __forceinline__ void gld_lds16(const void* g, void* l) {
    // async global->LDS, 16B per lane; LDS dest must be uniform_base + lane*16
    __builtin_amdgcn_global_load_lds((const __attribute__((address_space(1))) unsigned int*)g,
                                     (__attribute__((address_space(3))) unsigned int*)l,
                                     16, 0, 0);
}

__device__ __forceinline__ unsigned short f32_to_bf16_bits(float f) {
    unsigned u = __builtin_bit_cast(unsigned, f);
    u += 0x7fffu + ((u >> 16) & 1u);      // RNE; inputs are finite
    return (unsigned short)(u >> 16);
}

__device__ __forceinline__ unsigned pack_bf2(float a, float b) {
    return (unsigned)f32_to_bf16_bits(a) | ((unsigned)f32_to_bf16_bits(b) << 16);
}

__device__ __forceinline__ unsigned cvt_pk_bf16(float lo, float hi) {
    // dst = { [15:0]=bf16(lo), [31:16]=bf16(hi) }, RNE — same as pack_bf2
    unsigned r;
    asm("v_cvt_pk_bf16_f32 %0, %1, %2" : "=v"(r) : "v"(lo), "v"(hi));
    return r;
}

// ---------------------------------------------------------------------------
// 128x128 GEMM, 2-buffer DEEP-PREFETCH (counted vmcnt, T4 retrofit):
//   prologue: STAGE(b0,0); STAGE(b1,1)
//   iter kt:  vmcnt(8) [last: 0]; s_barrier      <- stage(kt) landed; stage(kt+1)
//             16 ds_read frags from buf[cur];       stays IN FLIGHT (never 0)
//             lgkmcnt(0); s_barrier              <- all waves consumed buf[cur]
//             STAGE(cur, kt+2); 32 MFMA          <- refill cur TWO tiles ahead
// Every stage gets ~2 full iterations of cover (vs <1 ds+MFMA block in r4).
// Ledger (8 loads/stage/thread, FIFO per m135): top of iter kt outstanding =
// stage(kt)+stage(kt+1)=16 -> vmcnt(8) retires exactly stage(kt).
// Race-freedom: writes into cur only issued after the barrier that follows
// every wave's lgkmcnt(0) for its reads of cur.
// LDS [2][128][64] x (A,B) = 64 KiB -> 2 blocks/CU.  XOR-8 swizzle on the
// per-lane GLOBAL source, linear gld_lds dest, same XOR on ds_read_b128 ->
// 0 bank conflicts (verified r2-r4).
// C[M,N] = A[M,K](bf16) @ Bt[N,K]^T(bf16) + bias; optional residual(fp32,
// in-place ok), exact GELU, fp32/bf16 outputs.  M==8192 (64 m-tiles),
// N%128==0, K%128==0 (NT>=2).  Grid = 64*(N/128), XCD-swizzled.
// ---------------------------------------------------------------------------
template <bool RES, bool GELU, bool WF, bool WH>
__global__ __launch_bounds__(256, 2) void gemm_bt(const __hip_bfloat16* __restrict__ A,
                                                  const __hip_bfloat16* __restrict__ Bt,
                                                  const float* __restrict__ bias,
                                                  const float* __restrict__ res,
                                                  float* __restrict__ outf,
                                                  __hip_bfloat16* __restrict__ outh,
                                                  int N, int K) {
    __shared__ __hip_bfloat16 lA[2][128 * 64];
    __shared__ __hip_bfloat16 lB[2][128 * 64];
    const int t = threadIdx.x;
    const int w = t >> 6, l = t & 63;
    const int lr = l & 15, lg = l >> 4;
    const int x7 = lr & 7;
    const int cs0 = (lg ^ x7) << 3;        // swizzled col offset (elems), ks=0
    const int cs1 = ((4 | lg) ^ x7) << 3;  // swizzled col offset (elems), ks=1
    // XCD-aware decode: 64 m-tiles total, 8 per XCD
    const int bid = blockIdx.x;
    const int xcd = bid & 7;
    const int local = bid >> 3;
    const int m0 = (xcd * 8 + (local & 7)) * 128;
    const int n0 = (local >> 3) * 128;
    const int wm = (w & 1) * 64, wn = (w >> 1) * 64;

    // staging: tile [128][64] = 1024 chunks of 16B; thread owns c = t + j*256.
    // chunk c: row = c>>3, phys slot = c&7; global col = (slot^(row&7))*8.
    const int srow = t >> 3, sslot = t & 7;       // row&7 == srow&7 (j*32 mult of 8)
    const int sx = (sslot ^ (srow & 7)) << 3;

    f32x4 acc[4][4];
#pragma unroll
    for (int i = 0; i < 4; i++)
#pragma unroll
        for (int j = 0; j < 4; j++) acc[i][j] = (f32x4){0.f, 0.f, 0.f, 0.f};

#define STAGE(buf, kt)                                                        \
    {                                                                         \
        _Pragma("unroll") for (int j = 0; j < 4; j++) {                       \
            const int row = srow + j * 32;                                    \
            const int gcol = (kt) * 64 + sx;                                  \
            gld_lds16(&A[(size_t)(m0 + row) * K + gcol], &lA[buf][(t + j * 256) * 8]); \
            gld_lds16(&Bt[(size_t)(n0 + row) * K + gcol], &lB[buf][(t + j * 256) * 8]); \
        }                                                                     \
    }

    // prologue: two tiles in flight
    STAGE(0, 0);
    STAGE(1, 1);

    const int NT = K >> 6;
    for (int kt = 0; kt < NT; ++kt) {
        const int cur = kt & 1;
        // stage(kt) must have landed; keep stage(kt+1) in flight (counted wait)
        if (kt + 1 < NT) { asm volatile("s_waitcnt vmcnt(8)" ::: "memory"); }
        else             { asm volatile("s_waitcnt vmcnt(0)" ::: "memory"); }
        __builtin_amdgcn_s_barrier();
        __builtin_amdgcn_sched_barrier(0);
        const __hip_bfloat16* sA = lA[cur];
        const __hip_bfloat16* sB = lB[cur];
        bf16x8 af[4][2], bf[4][2];
#pragma unroll
        for (int mt = 0; mt < 4; mt++) {
            const int ro = (wm + mt * 16 + lr) * 64;
            af[mt][0] = *(const bf16x8*)&sA[ro + cs0];
            af[mt][1] = *(const bf16x8*)&sA[ro + cs1];
        }
#pragma unroll
        for (int nt = 0; nt < 4; nt++) {
            const int ro = (wn + nt * 16 + lr) * 64;
            bf[nt][0] = *(const bf16x8*)&sB[ro + cs0];
            bf[nt][1] = *(const bf16x8*)&sB[ro + cs1];
        }
        asm volatile("s_waitcnt lgkmcnt(0)" ::: "memory");
        __builtin_amdgcn_sched_barrier(0);
        __builtin_amdgcn_s_barrier();       // all waves consumed buf[cur]
        if (kt + 2 < NT) STAGE(cur, kt + 2);  // refill 2 tiles ahead
#pragma unroll
        for (int mt = 0; mt < 4; mt++)
#pragma unroll
            for (int nt = 0; nt < 4; nt++) {
                acc[mt][nt] = MFMA16(af[mt][0], bf[nt][0], acc[mt][nt]);
                acc[mt][nt] = MFMA16(af[mt][1], bf[nt][1], acc[mt][nt]);
            }
    }
#undef STAGE

    // epilogue: C/D layout col=lane&15, row=(lane>>4)*4+reg  [m89/m91 verified]
#pragma unroll
    for (int nt = 0; nt < 4; nt++) {
        const int col = n0 + wn + nt * 16 + lr;
        const float bv = bias[col];
#pragma unroll
        for (int mt = 0; mt < 4; mt++) {
#pragma unroll
            for (int r = 0; r < 4; r++) {
                const int row = m0 + wm + mt * 16 + lg * 4 + r;
                const size_t idx = (size_t)row * N + col;
                float v = acc[mt][nt][r] + bv;
                if (RES) v += res[idx];
                if (GELU) v = 0.5f * v * (1.f + erff(v * 0.70710678118654752f));
                if (WF) outf[idx] = v;
                if (WH) outh[idx] = __float2bfloat16(v);
            }
        }
    }
}

// ---------------------------------------------------------------------------
// LayerNorm over W=768: one WAVE per row (4 rows/block), float4 loads, no LDS.
// ---------------------------------------------------------------------------
__global__ __launch_bounds__(256) void ln_kernel(const float* __restrict__ h,
                                                 const float* __restrict__ g,
                                                 const float* __restrict__ b,
                                                 __hip_bfloat16* __restrict__ y) {
    const int t = threadIdx.x;
    const int w = t >> 6, l = t & 63;
    const int row = blockIdx.x * 4 + w;
    const float4* hr = (const float4*)(h + (size_t)row * 768);
    const float4* g4 = (const float4*)g;
    const float4* b4 = (const float4*)b;
    float4 x[3];
    float s = 0.f, q = 0.f;
#pragma unroll
    for (int j = 0; j < 3; j++) {
        x[j] = hr[l + j * 64];
        s += x[j].x + x[j].y + x[j].z + x[j].w;
        q += x[j].x * x[j].x + x[j].y * x[j].y + x[j].z * x[j].z + x[j].w * x[j].w;
    }
#pragma unroll
    for (int d = 1; d < 64; d <<= 1) {
        s += __shfl_xor(s, d);
        q += __shfl_xor(q, d);
    }
    const float mean = s * (1.f / 768.f);
    const float var = q * (1.f / 768.f) - mean * mean;
    const float rs = rsqrtf(var + 1e-5f);
    uint2* yr = (uint2*)(y + (size_t)row * 768);
#pragma unroll
    for (int j = 0; j < 3; j++) {
        const float4 gg = g4[l + j * 64], bb = b4[l + j * 64];
        float o0 = (x[j].x - mean) * rs * gg.x + bb.x;
        float o1 = (x[j].y - mean) * rs * gg.y + bb.y;
        float o2 = (x[j].z - mean) * rs * gg.z + bb.z;
        float o3 = (x[j].w - mean) * rs * gg.w + bb.w;
        yr[l + j * 64] = make_uint2(pack_bf2(o0, o1), pack_bf2(o2, o3));
    }
}

// ---------------------------------------------------------------------------
// Per-layer weight transpose+convert: W[K,N] fp32 -> Wt[N,K] bf16 (4 matrices).
// ---------------------------------------------------------------------------
__global__ __launch_bounds__(256) void transpose_weights(const float* __restrict__ sq,
                                                         const float* __restrict__ so,
                                                         const float* __restrict__ sf,
                                                         const float* __restrict__ sp,
                                                         __hip_bfloat16* __restrict__ dq,
                                                         __hip_bfloat16* __restrict__ dO,
                                                         __hip_bfloat16* __restrict__ df,
                                                         __hip_bfloat16* __restrict__ dp) {
    const int bid = blockIdx.x;
    const float* src;
    __hip_bfloat16* dst;
    int K, N, tloc;
    if (bid < 1728)      { src = sq; dst = dq; K = 768;  N = 2304; tloc = bid; }
    else if (bid < 2304) { src = so; dst = dO; K = 768;  N = 768;  tloc = bid - 1728; }
    else if (bid < 4608) { src = sf; dst = df; K = 768;  N = 3072; tloc = bid - 2304; }
    else                 { src = sp; dst = dp; K = 3072; N = 768;  tloc = bid - 4608; }
    const int ktiles = K / 32;
    const int k0 = (tloc % ktiles) * 32;
    const int n0 = (tloc / ktiles) * 32;
    const int t = threadIdx.x;
    __shared__ float tile[32][33];
#pragma unroll
    for (int p = 0; p < 4; p++) {
        int rr = p * 8 + (t >> 5);
        tile[rr][t & 31] = src[(size_t)(k0 + rr) * N + n0 + (t & 31)];
    }
    __syncthreads();
#pragma unroll
    for (int p = 0; p < 4; p++) {
        int rr = p * 8 + (t >> 5);
        dst[(size_t)(n0 + rr) * K + k0 + (t & 31)] = __float2bfloat16(tile[t & 31][rr]);
    }
}

// ---------------------------------------------------------------------------
// V transpose: qkv[b,n, h*192+128+c] -> vt[(b*12+h)*64+c, n]   (bf16 bits)
// ---------------------------------------------------------------------------
__global__ __launch_bounds__(256) void vt_transpose(const short* __restrict__ qkv,
                                                    short* __restrict__ vt) {
    const int bid = blockIdx.x;           // 96 bh * 64 tiles
    const int bh = bid >> 6, tau = bid & 63;
    const int b = bh / 12, h = bh % 12;
    const int ct = tau >> 5, nt = tau & 31;
    const int n0 = nt * 32, c0 = ct * 32;
    const int t = threadIdx.x;
    __shared__ short tile[32][33];
    const short* base = qkv + (size_t)(b * 1024 + n0) * 2304 + h * 192 + 128 + c0;
#pragma unroll
    for (int p = 0; p < 4; p++) {
        int rr = p * 8 + (t >> 5);
        tile[rr][t & 31] = base[(size_t)rr * 2304 + (t & 31)];
    }
    __syncthreads();
    short* ob = vt + (size_t)((b * 12 + h) * 64 + c0) * 1024 + n0;
#pragma unroll
    for (int p = 0; p < 4; p++) {
        int rr = p * 8 + (t >> 5);
        ob[(size_t)rr * 1024 + (t & 31)] = tile[t & 31][rr];
    }
}

// ---------------------------------------------------------------------------
// Flash attention, S^T formulation, now with K/V DOUBLE-BUFFER + counted
// vmcnt (same ledger as gemm_bt: 4 loads/stage, vmcnt(4) in the loop, stage
// kt+2 into the just-consumed buffer after the consumption barrier).
// Workgroup = (64 queries, head, batch); 4 waves x 16 queries.
// ---------------------------------------------------------------------------
__global__ __launch_bounds__(256) void attn_kernel(const short* __restrict__ qkv,
                                                   const short* __restrict__ vt,
                                                   short* __restrict__ attnout) {
    const int bid = blockIdx.x;           // 1536
    const int xcd = bid & 7, j = bid >> 3;
    const int bh = xcd * 12 + (j >> 4);
    const int qt = j & 15;
    const int b = bh / 12, hh = bh % 12;
    const int t = threadIdx.x, w = t >> 6, l = t & 63;
    const int lr = l & 15, lg = l >> 4;
    const int x7 = lr & 7;
    __shared__ short lK[2][64 * 64];       // [dbuf][key][dim], XOR-swizzled content
    __shared__ short lV[2][64 * 64];       // [dbuf][dim][key], XOR-swizzled content
    __shared__ short lP[4][16 * 64];       // per-wave P, [q][key], XOR-swizzled
    const int qw = qt * 64 + w * 16;

    bf16x8 bq[2];
#pragma unroll
    for (int ks = 0; ks < 2; ks++)
        bq[ks] = *(const bf16x8*)&qkv[(size_t)(b * 1024 + qw + lr) * 2304 + hh * 192 + ks * 32 + lg * 8];

    int col[2];
    col[0] = (lg ^ x7) * 8;
    col[1] = ((4 | lg) ^ x7) * 8;

    const int c0 = t, c1 = t + 256;
    const int r0 = c0 >> 3, r1 = c1 >> 3;
    const int s0 = (c0 & 7) ^ (r0 & 7), s1 = (c1 & 7) ^ (r1 & 7);
    const short* gK0 = qkv + (size_t)(b * 1024 + r0) * 2304 + hh * 192 + 64 + s0 * 8;
    const short* gK1 = qkv + (size_t)(b * 1024 + r1) * 2304 + hh * 192 + 64 + s1 * 8;
    const short* gV0 = vt + (size_t)((b * 12 + hh) * 64 + r0) * 1024 + s0 * 8;
    const short* gV1 = vt + (size_t)((b * 12 + hh) * 64 + r1) * 1024 + s1 * 8;

#define STAGE_KV(buf, kt)                                           \
    {                                                               \
        const int key0_ = (kt) * 64;                                \
        gld_lds16(gK0 + (size_t)key0_ * 2304, &lK[buf][c0 * 8]);    \
        gld_lds16(gK1 + (size_t)key0_ * 2304, &lK[buf][c1 * 8]);    \
        gld_lds16(gV0 + key0_, &lV[buf][c0 * 8]);                   \
        gld_lds16(gV1 + key0_, &lV[buf][c1 * 8]);                   \
    }

    f32x4 o[4];
#pragma unroll
    for (int dt = 0; dt < 4; dt++) o[dt] = (f32x4){0.f, 0.f, 0.f, 0.f};
    const float cexp = 0.125f * 1.44269504088896f;  // scale^2 * log2(e)
    float cm = -1.0e30f;   // running c*max, per-lane query q=lr
    float lsum = 0.f;

    // prologue: two K/V tiles in flight
    STAGE_KV(0, 0);
    STAGE_KV(1, 1);

    for (int kt = 0; kt < 16; kt++) {
        const int cur = kt & 1;
        // stage(kt) landed; keep stage(kt+1) in flight
        if (kt < 15) { asm volatile("s_waitcnt vmcnt(4)" ::: "memory"); }
        else         { asm volatile("s_waitcnt vmcnt(0)" ::: "memory"); }
        __builtin_amdgcn_s_barrier();
        __builtin_amdgcn_sched_barrier(0);

        // S^T = K Q^T: lane holds S^T[key=nt*16+lg*4+r][q=lr]
        f32x4 s[4];
#pragma unroll
        for (int nt = 0; nt < 4; nt++) s[nt] = (f32x4){0.f, 0.f, 0.f, 0.f};
#pragma unroll
        for (int nt = 0; nt < 4; nt++)
#pragma unroll
            for (int ks = 0; ks < 2; ks++) {
                bf16x8 ak = *(const bf16x8*)&lK[cur][(nt * 16 + lr) * 64 + col[ks]];
                s[nt] = MFMA16(ak, bq[ks], s[nt]);
            }

        float mx = s[0][0];
#pragma unroll
        for (int nt = 0; nt < 4; nt++)
#pragma unroll
            for (int r = 0; r < 4; r++) mx = fmaxf(mx, s[nt][r]);
        mx = fmaxf(mx, __shfl_xor(mx, 16));
        mx = fmaxf(mx, __shfl_xor(mx, 32));
        const float tm = mx * cexp;
        if (!__all(tm <= cm + 8.f)) {
            const float cmn = fmaxf(cm, tm);
            const float alpha = exp2f(cm - cmn);   // first tile: exp2(-inf)=0
            cm = cmn;
            lsum *= alpha;
            float af[4];
#pragma unroll
            for (int r = 0; r < 4; r++) af[r] = __shfl(alpha, lg * 4 + r);
#pragma unroll
            for (int dt = 0; dt < 4; dt++)
#pragma unroll
                for (int r = 0; r < 4; r++) o[dt][r] *= af[r];
        }
        float ps = 0.f;
#pragma unroll
        for (int nt = 0; nt < 4; nt++)
#pragma unroll
            for (int r = 0; r < 4; r++) {
                float p = exp2f(s[nt][r] * cexp - cm);   // bounded by 2^8
                s[nt][r] = p;
                ps += p;
            }
        ps += __shfl_xor(ps, 16);
        ps += __shfl_xor(ps, 32);
        lsum += ps;

#pragma unroll
        for (int nt = 0; nt < 4; nt++) {
            unsigned pk0 = cvt_pk_bf16(s[nt][0], s[nt][1]);
            unsigned pk1 = cvt_pk_bf16(s[nt][2], s[nt][3]);
            const int S = nt * 2 + (lg >> 1);
            *(uint2*)&lP[w][lr * 64 + ((S ^ x7) << 3) + ((lg & 1) << 2)] = make_uint2(pk0, pk1);
        }

#pragma unroll
        for (int kc = 0; kc < 2; kc++) {
            bf16x8 ap = *(const bf16x8*)&lP[w][lr * 64 + col[kc]];
#pragma unroll
            for (int dt = 0; dt < 4; dt++) {
                bf16x8 bv = *(const bf16x8*)&lV[cur][(dt * 16 + lr) * 64 + col[kc]];
                o[dt] = MFMA16(ap, bv, o[dt]);
            }
        }

        asm volatile("s_waitcnt lgkmcnt(0)" ::: "memory");
        __builtin_amdgcn_sched_barrier(0);
        __builtin_amdgcn_s_barrier();       // all waves consumed lK/lV[cur]
        if (kt + 2 < 16) STAGE_KV(cur, kt + 2);
    }
#undef STAGE_KV

    float inv[4];
#pragma unroll
    for (int r = 0; r < 4; r++) inv[r] = 1.f / __shfl(lsum, lg * 4 + r);
#pragma unroll
    for (int dt = 0; dt < 4; dt++)
#pragma unroll
        for (int r = 0; r < 4; r++)
            attnout[(size_t)(b * 1024 + qw + lg * 4 + r) * 768 + hh * 64 + dt * 16 + lr] =
                (short)f32_to_bf16_bits(o[dt][r] * inv[r]);
}

// ---------------------------------------------------------------------------
// Host
// ---------------------------------------------------------------------------
extern "C" void kernel_launch(void* const* d_in, const int* in_sizes, int n_in,
                              void* d_out, int out_size, void* d_ws, size_t ws_size,
                              hipStream_t stream) {
    const float* x    = (const float*)d_in[0];
    const float* Wqkv = (const float*)d_in[1];
    const float* bqkv = (const float*)d_in[2];
    const float* Wo   = (const float*)d_in[3];
    const float* bo   = (const float*)d_in[4];
    const float* Wfc  = (const float*)d_in[5];
    const float* bfc  = (const float*)d_in[6];
    const float* Wpr  = (const float*)d_in[7];
    const float* bpr  = (const float*)d_in[8];
    const float* g1   = (const float*)d_in[9];
    const float* b1   = (const float*)d_in[10];
    const float* g2   = (const float*)d_in[11];
    const float* b2   = (const float*)d_in[12];
    float* h = (float*)d_out;   // h lives in d_out throughout

    char* ws = (char*)d_ws;
    size_t off = 0;
    auto alloc = [&](size_t bytes) -> void* {
        void* p = ws + off;
        off += (bytes + 255) & ~(size_t)255;
        return p;
    };
    __hip_bfloat16* tQKV = (__hip_bfloat16*)alloc((size_t)2304 * 768 * 2);
    __hip_bfloat16* tO   = (__hip_bfloat16*)alloc((size_t)768 * 768 * 2);
    __hip_bfloat16* tFC  = (__hip_bfloat16*)alloc((size_t)3072 * 768 * 2);
    __hip_bfloat16* tPR  = (__hip_bfloat16*)alloc((size_t)768 * 3072 * 2);
    __hip_bfloat16* y    = (__hip_bfloat16*)alloc((size_t)8192 * 768 * 2);
    __hip_bfloat16* att  = (__hip_bfloat16*)alloc((size_t)8192 * 768 * 2);
    __hip_bfloat16* vtb  = (__hip_bfloat16*)alloc((size_t)8192 * 768 * 2);
    __hip_bfloat16* big  = (__hip_bfloat16*)alloc((size_t)8192 * 3072 * 2); // qkv & fc share
    __hip_bfloat16* qkvb = big;
    __hip_bfloat16* fcb  = big;

    hipMemcpyAsync(h, x, (size_t)8 * 1024 * 768 * 4, hipMemcpyDeviceToDevice, stream);

    for (int L = 0; L < 8; L++) {
        const float* wq = Wqkv + (size_t)L * 768 * 2304;
        const float* wo = Wo   + (size_t)L * 768 * 768;
        const float* wf = Wfc  + (size_t)L * 768 * 3072;
        const float* wp = Wpr  + (size_t)L * 3072 * 768;

        transpose_weights<<<6912, 256, 0, stream>>>(wq, wo, wf, wp, tQKV, tO, tFC, tPR);

        ln_kernel<<<2048, 256, 0, stream>>>(h, g1 + L * 768, b1 + L * 768, y);

        gemm_bt<false, false, false, true><<<18 * 64, 256, 0, stream>>>(
            y, tQKV, bqkv + L * 2304, nullptr, nullptr, qkvb, 2304, 768);

        vt_transpose<<<6144, 256, 0, stream>>>((const short*)qkvb, (short*)vtb);

        attn_kernel<<<1536, 256, 0, stream>>>(
            (const short*)qkvb, (const short*)vtb, (short*)att);

        gemm_bt<true, false, true, false><<<6 * 64, 256, 0, stream>>>(
            att, tO, bo + L * 768, h, h, nullptr, 768, 768);

        ln_kernel<<<2048, 256, 0, stream>>>(h, g2 + L * 768, b2 + L * 768, y);

        gemm_bt<false, true, false, true><<<24 * 64, 256, 0, stream>>>(
            y, tFC, bfc + L * 3072, nullptr, nullptr, fcb, 3072, 768);

        gemm_bt<true, false, true, false><<<6 * 64, 256, 0, stream>>>(
            fcb, tPR, bpr + L * 768, h, h, nullptr, 768, 3072);
    }
}